// Round 6
// baseline (630.077 us; speedup 1.0000x reference)
//
#include <hip/hip_runtime.h>

#define T 64
#define F_IN 3
#define H 16
#define G 48
#define D2 32
#define DEPTH 5
#define NCLS 4

// LDS geometry (f16 element units)
#define YST 32          // f16 per t-row (64 B rows)
#define YSB 2056        // f16 per batch elem (64*32 + 8 pad)
#define HZ_ZOFF 64      // zero block inside hzb

typedef _Float16 half8 __attribute__((ext_vector_type(8)));
typedef _Float16 half4v __attribute__((ext_vector_type(4)));
typedef float f32x4v __attribute__((ext_vector_type(4)));

__device__ __forceinline__ float fast_sigmoid(float x) {
    return __fdividef(1.0f, 1.0f + __expf(-x));
}
__device__ __forceinline__ float fast_tanh(float x) {
    return 1.0f - __fdividef(2.0f, 1.0f + __expf(2.0f * x));
}

// One wave per WG, 4 jobs: job = quad, lb = quad&1, dir = quad>>1.
// gx: per-4-step chunk, 6 MFMAs land gx[job][t][gate] in the consuming lane's
//     registers; layer bias rides in the MFMA C operand (invariant splat).
// gh: per step, 1 ds_read_b128 of h (hzb) + 3 MFMAs; direction split in
//     K-space (fwd k<16 / bwd k>=16, invalid half reads zeros); bh_n rides in
//     the n-gate MFMA's C operand.
// Occupancy: SINGLE y LDS buffer; each layer's output accumulates in 32
//     packed VGPRs (ypk, static indices via full unroll) and is dumped to the
//     y buffer at layer end — in-place safe (all reads precede dump, one wave,
//     in-order DS). LDS ~9.4 KB -> 4 waves/SIMD.
// Single wave per WG => lockstep => no __syncthreads() anywhere.
__global__ __launch_bounds__(64, 4) void bigru_all(
    const float* __restrict__ x,
    const float* __restrict__ Wi1, const float* __restrict__ Wh1,
    const float* __restrict__ bi1, const float* __restrict__ bh1,
    const float* __restrict__ Wi5, const float* __restrict__ Wh5,
    const float* __restrict__ bi5, const float* __restrict__ bh5,
    const float* __restrict__ Wc,  const float* __restrict__ bc,
    float* __restrict__ out)
{
    __shared__ __align__(16) _Float16 yb[2 * YSB];
    __shared__ __align__(16) _Float16 hzb[80];     // [0,64): h[job][16]; [64,72): zeros
    __shared__ __align__(16) _Float16 xs[2 * T * 4];

    const int lane = threadIdx.x;
    const int j15  = lane & 15;
    const int quad = lane >> 4;
    const int lb   = quad & 1;
    const int dir  = quad >> 1;
    const bool isf = (dir == 0);

    // ---- stage x[2][T][3] -> xs[2][T][4] (f16); zero h + zero block
    {
        const float* xg = x + (size_t)blockIdx.x * (2 * T * F_IN);
        for (int idx = lane; idx < 2 * T * F_IN; idx += 64) {
            int bb = idx / (T * F_IN);
            int r  = idx - bb * (T * F_IN);
            int tt = r / F_IN;
            int c  = r - tt * F_IN;
            xs[bb * (T * 4) + tt * 4 + c] = (_Float16)xg[idx];
        }
        hzb[lane] = (_Float16)0.0f;
        if (lane < 16) hzb[64 + lane] = (_Float16)0.0f;
    }

    // gh A-frag source (loop-invariant): lane supplies A[m=j15][k=quad*8+..7]
    const int  job_a  = j15 >> 2;
    const bool avalid = ((j15 >> 3) == 0) ? (quad < 2) : (quad >= 2);
    const _Float16* aptr = hzb + (avalid ? (job_a * 16 + (quad & 1) * 8) : HZ_ZOFF);

    const int ystep = isf ? YST : -YST;
    const f32x4v zC = {0.f, 0.f, 0.f, 0.f};

    float hj;

    // ================= layer 1 (gx scalar from xs, gh via MFMA) =============
    {
        half8 whB[3];
        {
            const float* wsrc = Wh1 + ((quad < 2) ? 0 : G * H);
            #pragma unroll
            for (int g = 0; g < 3; ++g) {
                const float* w = wsrc + (g * 16 + j15) * H + (quad & 1) * 8;
                half8 hv;
                #pragma unroll
                for (int i = 0; i < 8; ++i) hv[i] = (_Float16)w[i];
                whB[g] = hv;
            }
        }
        float wi[3][F_IN];
        float bir[3], bhr2;
        {
            const float* Wi = Wi1 + dir * (G * F_IN);
            const float* bi = bi1 + dir * G;
            const float* bh = bh1 + dir * G;
            #pragma unroll
            for (int g = 0; g < 3; ++g) {
                int row = g * H + j15;
                #pragma unroll
                for (int k = 0; k < F_IN; ++k) wi[g][k] = Wi[row * F_IN + k];
                bir[g] = bi[row] + ((g < 2) ? bh[row] : 0.0f);
            }
            bhr2 = bh[2 * H + j15];
        }
        const f32x4v cN = {bhr2, bhr2, bhr2, bhr2};
        hj = 0.0f;

        _Float16* yw = yb + lb * YSB + (isf ? 0 : (T - 1)) * YST + dir * H + j15;

        #pragma unroll 2
        for (int s = 0; s < T; ++s) {
            int t = isf ? s : (T - 1 - s);
            half4v xv = ((const half4v*)xs)[lb * T + t];
            float x0 = (float)xv[0], x1 = (float)xv[1], x2 = (float)xv[2];
            float gxr = fmaf(wi[0][2], x2, fmaf(wi[0][1], x1, fmaf(wi[0][0], x0, bir[0])));
            float gxz = fmaf(wi[1][2], x2, fmaf(wi[1][1], x1, fmaf(wi[1][0], x0, bir[1])));
            float gxn = fmaf(wi[2][2], x2, fmaf(wi[2][1], x1, fmaf(wi[2][0], x0, bir[2])));
            half8 a = *(const half8*)aptr;
            f32x4v d0 = __builtin_amdgcn_mfma_f32_16x16x32_f16(a, whB[0], zC, 0, 0, 0);
            f32x4v d1 = __builtin_amdgcn_mfma_f32_16x16x32_f16(a, whB[1], zC, 0, 0, 0);
            f32x4v d2 = __builtin_amdgcn_mfma_f32_16x16x32_f16(a, whB[2], cN, 0, 0, 0);
            float rg = fast_sigmoid(gxr + d0[0]);
            float zg = fast_sigmoid(gxz + d1[0]);
            float ng = fast_tanh(fmaf(rg, d2[0], gxn));
            float hn = fmaf(zg, hj - ng, ng);
            hj = hn;
            _Float16 hh = (_Float16)hn;
            hzb[lane] = hh;
            *yw = hh;       // no in-place hazard: layer 1 never reads yb
            yw += ystep;
        }
    }

    // ================= layers 2..6 =================
    #pragma unroll 1
    for (int l = 0; l < DEPTH; ++l) {
        // gx B-frags (both dirs)
        half8 bf[2][3];
        #pragma unroll
        for (int d = 0; d < 2; ++d) {
            #pragma unroll
            for (int g = 0; g < 3; ++g) {
                const float* w = Wi5 + ((size_t)(l * 2 + d) * G + g * 16 + j15) * D2 + quad * 8;
                half8 hv;
                #pragma unroll
                for (int i = 0; i < 8; ++i) hv[i] = (_Float16)w[i];
                bf[d][g] = hv;
            }
        }
        // gh B-frags (dir split by quad-half)
        half8 whB[3];
        {
            const float* wsrc = Wh5 + (size_t)(l * 2) * G * H + ((quad < 2) ? 0 : G * H);
            #pragma unroll
            for (int g = 0; g < 3; ++g) {
                const float* w = wsrc + (g * 16 + j15) * H + (quad & 1) * 8;
                half8 hv;
                #pragma unroll
                for (int i = 0; i < 8; ++i) hv[i] = (_Float16)w[i];
                whB[g] = hv;
            }
        }
        // own-dir biases -> invariant C splats
        float bib0, bib1, bib2, bhr2;
        {
            const float* biL = bi5 + (l * 2 + dir) * G;
            const float* bhL = bh5 + (l * 2 + dir) * G;
            bib0 = biL[j15]         + bhL[j15];
            bib1 = biL[H + j15]     + bhL[H + j15];
            bib2 = biL[2 * H + j15];
            bhr2 = bhL[2 * H + j15];
        }
        const f32x4v cR = {bib0, bib0, bib0, bib0};
        const f32x4v cZ = {bib1, bib1, bib1, bib1};
        const f32x4v cNx = {bib2, bib2, bib2, bib2};
        const f32x4v cN = {bhr2, bhr2, bhr2, bhr2};

        hj = 0.0f;
        hzb[lane] = (_Float16)0.0f;

        const int lb_a = (j15 >> 2) & 1;
        const int tl_a = j15 & 3;

        unsigned int ypk[T / 2];    // this job's output, packed 2 f16/reg, step order

        #pragma unroll
        for (int c = 0; c < T / 4; ++c) {
            const int tf = 4 * c;
            const int tb = T - 4 - 4 * c;
            const int row = (j15 < 8) ? (tf + tl_a) : (tb + tl_a);
            half8 ax = *(const half8*)(yb + lb_a * YSB + row * YST + quad * 8);
            f32x4v c0f = __builtin_amdgcn_mfma_f32_16x16x32_f16(ax, bf[0][0], cR, 0, 0, 0);
            f32x4v c1f = __builtin_amdgcn_mfma_f32_16x16x32_f16(ax, bf[0][1], cZ, 0, 0, 0);
            f32x4v c2f = __builtin_amdgcn_mfma_f32_16x16x32_f16(ax, bf[0][2], cNx, 0, 0, 0);
            f32x4v c0b = __builtin_amdgcn_mfma_f32_16x16x32_f16(ax, bf[1][0], cR, 0, 0, 0);
            f32x4v c1b = __builtin_amdgcn_mfma_f32_16x16x32_f16(ax, bf[1][1], cZ, 0, 0, 0);
            f32x4v c2b = __builtin_amdgcn_mfma_f32_16x16x32_f16(ax, bf[1][2], cNx, 0, 0, 0);
            float gx0[4], gx1[4], gx2[4];
            #pragma unroll
            for (int s = 0; s < 4; ++s) {
                gx0[s] = isf ? c0f[s] : c0b[3 - s];
                gx1[s] = isf ? c1f[s] : c1b[3 - s];
                gx2[s] = isf ? c2f[s] : c2b[3 - s];
            }

            #pragma unroll
            for (int s = 0; s < 4; ++s) {
                half8 a = *(const half8*)aptr;
                f32x4v d0 = __builtin_amdgcn_mfma_f32_16x16x32_f16(a, whB[0], zC, 0, 0, 0);
                f32x4v d1 = __builtin_amdgcn_mfma_f32_16x16x32_f16(a, whB[1], zC, 0, 0, 0);
                f32x4v d2 = __builtin_amdgcn_mfma_f32_16x16x32_f16(a, whB[2], cN, 0, 0, 0);
                float rg = fast_sigmoid(gx0[s] + d0[0]);
                float zg = fast_sigmoid(gx1[s] + d1[0]);
                float ng = fast_tanh(fmaf(rg, d2[0], gx2[s]));
                float hn = fmaf(zg, hj - ng, ng);
                hj = hn;
                _Float16 hh = (_Float16)hn;
                hzb[lane] = hh;
                unsigned int hb16 = (unsigned int)__builtin_bit_cast(unsigned short, hh);
                const int k = 4 * c + s;          // static
                if (k & 1) ypk[k >> 1] |= hb16 << 16;
                else       ypk[k >> 1]  = hb16;
            }
        }

        // ---- dump this layer's output into yb (prev layer fully consumed) ----
        {
            _Float16* yw = yb + lb * YSB + (isf ? 0 : (T - 1)) * YST + dir * H + j15;
            #pragma unroll
            for (int i = 0; i < T / 2; ++i) {
                unsigned int v = ypk[i];
                *yw = __builtin_bit_cast(_Float16, (unsigned short)(v & 0xffffu));
                yw += ystep;
                *yw = __builtin_bit_cast(_Float16, (unsigned short)(v >> 16));
                yw += ystep;
            }
        }
    }

    // ================= classifier + softmax (final y in yb) =================
    #pragma unroll
    for (int i = 0; i < 2; ++i) {
        int idx = lane + i * 64;
        int bb  = idx >> 6;
        int t   = idx & 63;
        const _Float16* yrow = yb + bb * YSB + t * YST;
        float yv[D2];
        #pragma unroll
        for (int k8 = 0; k8 < 4; ++k8) {
            half8 v = *(const half8*)(yrow + k8 * 8);
            #pragma unroll
            for (int i8 = 0; i8 < 8; ++i8) yv[k8 * 8 + i8] = (float)v[i8];
        }
        float lg[NCLS];
        #pragma unroll
        for (int c = 0; c < NCLS; ++c) {
            const float* wc = Wc + c * D2;
            float acc = bc[c];
            #pragma unroll
            for (int k = 0; k < D2; ++k) acc = fmaf(wc[k], yv[k], acc);
            lg[c] = acc;
        }
        float m = fmaxf(fmaxf(lg[0], lg[1]), fmaxf(lg[2], lg[3]));
        float e0 = __expf(lg[0] - m), e1 = __expf(lg[1] - m);
        float e2 = __expf(lg[2] - m), e3 = __expf(lg[3] - m);
        float inv = __fdividef(1.0f, e0 + e1 + e2 + e3);
        size_t bglob = (size_t)blockIdx.x * 2 + bb;
        float4 o;
        o.x = e0 * inv; o.y = e1 * inv; o.z = e2 * inv; o.w = e3 * inv;
        ((float4*)out)[bglob * T + t] = o;
    }
}

extern "C" void kernel_launch(void* const* d_in, const int* in_sizes, int n_in,
                              void* d_out, int out_size, void* d_ws, size_t ws_size,
                              hipStream_t stream) {
    const float* x   = (const float*)d_in[0];
    const float* Wi1 = (const float*)d_in[1];
    const float* Wh1 = (const float*)d_in[2];
    const float* bi1 = (const float*)d_in[3];
    const float* bh1 = (const float*)d_in[4];
    const float* Wi5 = (const float*)d_in[5];
    const float* Wh5 = (const float*)d_in[6];
    const float* bi5 = (const float*)d_in[7];
    const float* bh5 = (const float*)d_in[8];
    const float* Wc  = (const float*)d_in[9];
    const float* bc  = (const float*)d_in[10];
    float* out = (float*)d_out;

    const int B = in_sizes[0] / (T * F_IN);   // 16384
    dim3 grid(B / 2), block(64);
    hipLaunchKernelGGL(bigru_all, grid, block, 0, stream,
                       x, Wi1, Wh1, bi1, bh1, Wi5, Wh5, bi5, bh5, Wc, bc, out);
}

// Round 7
// 533.383 us; speedup vs baseline: 1.1813x; 1.1813x over previous
//
#include <hip/hip_runtime.h>

#define T 64
#define F_IN 3
#define H 16
#define G 48
#define D2 32
#define DEPTH 5
#define NCLS 4

// LDS geometry (f16 element units)
#define YST 32          // f16 per t-row (64 B rows)
#define YSB 2056        // f16 per batch elem (64*32 + 8 pad)
#define HZ_ZOFF 64      // zero block inside hzb

typedef _Float16 half8 __attribute__((ext_vector_type(8)));
typedef _Float16 half4v __attribute__((ext_vector_type(4)));
typedef float f32x4v __attribute__((ext_vector_type(4)));

__device__ __forceinline__ float fast_sigmoid(float x) {
    return __fdividef(1.0f, 1.0f + __expf(-x));
}
__device__ __forceinline__ float fast_tanh(float x) {
    return 1.0f - __fdividef(2.0f, 1.0f + __expf(2.0f * x));
}

// One wave per WG, 4 jobs: job = quad, lb = quad&1, dir = quad>>1.
// gx: per-4-step chunk, 6 MFMAs land gx[job][t][gate] in the consuming lane's
//     registers; biases ride in the MFMA C operand.
// gh: per step, 1 ds_read_b128 of h + 3 MFMAs (direction split in K-space).
// Occupancy: SINGLE y buffer. Steps k<32 park output in ypk[16] (static
//     indices, c=0..7 unrolled); steps k>=32 write IN-PLACE into yb (safe:
//     by chunk 8, the target rows' old values are consumed by both dirs;
//     chunk-top reads precede that chunk's writes; one wave, in-order DS).
//     Parked half dumps at layer end. LDS ~9.4 KB -> 16 WG/CU.
// Single wave per WG => lockstep => no __syncthreads() anywhere.
__global__ __launch_bounds__(64, 4) void bigru_all(
    const float* __restrict__ x,
    const float* __restrict__ Wi1, const float* __restrict__ Wh1,
    const float* __restrict__ bi1, const float* __restrict__ bh1,
    const float* __restrict__ Wi5, const float* __restrict__ Wh5,
    const float* __restrict__ bi5, const float* __restrict__ bh5,
    const float* __restrict__ Wc,  const float* __restrict__ bc,
    float* __restrict__ out)
{
    __shared__ __align__(16) _Float16 yb[2 * YSB];
    __shared__ __align__(16) _Float16 hzb[80];     // [0,64): h[job][16]; [64,72): zeros
    __shared__ __align__(16) _Float16 xs[2 * T * 4];

    const int lane = threadIdx.x;
    const int j15  = lane & 15;
    const int quad = lane >> 4;
    const int lb   = quad & 1;
    const int dir  = quad >> 1;
    const bool isf = (dir == 0);

    // ---- stage x[2][T][3] -> xs[2][T][4] (f16); zero h + zero block
    {
        const float* xg = x + (size_t)blockIdx.x * (2 * T * F_IN);
        for (int idx = lane; idx < 2 * T * F_IN; idx += 64) {
            int bb = idx / (T * F_IN);
            int r  = idx - bb * (T * F_IN);
            int tt = r / F_IN;
            int c  = r - tt * F_IN;
            xs[bb * (T * 4) + tt * 4 + c] = (_Float16)xg[idx];
        }
        hzb[lane] = (_Float16)0.0f;
        if (lane < 16) hzb[64 + lane] = (_Float16)0.0f;
    }

    // gh A-frag source (loop-invariant): lane supplies A[m=j15][k=quad*8+..7]
    const int  job_a  = j15 >> 2;
    const bool avalid = ((j15 >> 3) == 0) ? (quad < 2) : (quad >= 2);
    const _Float16* aptr = hzb + (avalid ? (job_a * 16 + (quad & 1) * 8) : HZ_ZOFF);

    const int ystep = isf ? YST : -YST;
    const f32x4v zC = {0.f, 0.f, 0.f, 0.f};

    float hj;

    // ================= layer 1 (gx scalar from xs, gh via MFMA) =============
    {
        half8 whB[3];
        {
            const float* wsrc = Wh1 + ((quad < 2) ? 0 : G * H);
            #pragma unroll
            for (int g = 0; g < 3; ++g) {
                const float* w = wsrc + (g * 16 + j15) * H + (quad & 1) * 8;
                half8 hv;
                #pragma unroll
                for (int i = 0; i < 8; ++i) hv[i] = (_Float16)w[i];
                whB[g] = hv;
            }
        }
        float wi[3][F_IN];
        float bir[3], bhr2;
        {
            const float* Wi = Wi1 + dir * (G * F_IN);
            const float* bi = bi1 + dir * G;
            const float* bh = bh1 + dir * G;
            #pragma unroll
            for (int g = 0; g < 3; ++g) {
                int row = g * H + j15;
                #pragma unroll
                for (int k = 0; k < F_IN; ++k) wi[g][k] = Wi[row * F_IN + k];
                bir[g] = bi[row] + ((g < 2) ? bh[row] : 0.0f);
            }
            bhr2 = bh[2 * H + j15];
        }
        const f32x4v cN = {bhr2, bhr2, bhr2, bhr2};
        hj = 0.0f;

        _Float16* yw = yb + lb * YSB + (isf ? 0 : (T - 1)) * YST + dir * H + j15;

        #pragma unroll 2
        for (int s = 0; s < T; ++s) {
            int t = isf ? s : (T - 1 - s);
            half4v xv = ((const half4v*)xs)[lb * T + t];
            float x0 = (float)xv[0], x1 = (float)xv[1], x2 = (float)xv[2];
            float gxr = fmaf(wi[0][2], x2, fmaf(wi[0][1], x1, fmaf(wi[0][0], x0, bir[0])));
            float gxz = fmaf(wi[1][2], x2, fmaf(wi[1][1], x1, fmaf(wi[1][0], x0, bir[1])));
            float gxn = fmaf(wi[2][2], x2, fmaf(wi[2][1], x1, fmaf(wi[2][0], x0, bir[2])));
            half8 a = *(const half8*)aptr;
            f32x4v d0 = __builtin_amdgcn_mfma_f32_16x16x32_f16(a, whB[0], zC, 0, 0, 0);
            f32x4v d1 = __builtin_amdgcn_mfma_f32_16x16x32_f16(a, whB[1], zC, 0, 0, 0);
            f32x4v d2 = __builtin_amdgcn_mfma_f32_16x16x32_f16(a, whB[2], cN, 0, 0, 0);
            float rg = fast_sigmoid(gxr + d0[0]);
            float zg = fast_sigmoid(gxz + d1[0]);
            float ng = fast_tanh(fmaf(rg, d2[0], gxn));
            float hn = fmaf(zg, hj - ng, ng);
            hj = hn;
            _Float16 hh = (_Float16)hn;
            hzb[lane] = hh;
            *yw = hh;       // layer 1 never reads yb -> no hazard
            yw += ystep;
        }
    }

    // ================= layers 2..6 =================
    #pragma unroll 1
    for (int l = 0; l < DEPTH; ++l) {
        // gx B-frags (both dirs)
        half8 bf[2][3];
        #pragma unroll
        for (int d = 0; d < 2; ++d) {
            #pragma unroll
            for (int g = 0; g < 3; ++g) {
                const float* w = Wi5 + ((size_t)(l * 2 + d) * G + g * 16 + j15) * D2 + quad * 8;
                half8 hv;
                #pragma unroll
                for (int i = 0; i < 8; ++i) hv[i] = (_Float16)w[i];
                bf[d][g] = hv;
            }
        }
        // gh B-frags (dir split by quad-half)
        half8 whB[3];
        {
            const float* wsrc = Wh5 + (size_t)(l * 2) * G * H + ((quad < 2) ? 0 : G * H);
            #pragma unroll
            for (int g = 0; g < 3; ++g) {
                const float* w = wsrc + (g * 16 + j15) * H + (quad & 1) * 8;
                half8 hv;
                #pragma unroll
                for (int i = 0; i < 8; ++i) hv[i] = (_Float16)w[i];
                whB[g] = hv;
            }
        }
        // own-dir biases -> invariant C splats
        float bib0, bib1, bib2, bhr2;
        {
            const float* biL = bi5 + (l * 2 + dir) * G;
            const float* bhL = bh5 + (l * 2 + dir) * G;
            bib0 = biL[j15]         + bhL[j15];
            bib1 = biL[H + j15]     + bhL[H + j15];
            bib2 = biL[2 * H + j15];
            bhr2 = bhL[2 * H + j15];
        }
        const f32x4v cR  = {bib0, bib0, bib0, bib0};
        const f32x4v cZ  = {bib1, bib1, bib1, bib1};
        const f32x4v cNx = {bib2, bib2, bib2, bib2};
        const f32x4v cN  = {bhr2, bhr2, bhr2, bhr2};

        hj = 0.0f;
        hzb[lane] = (_Float16)0.0f;

        const int lb_a = (j15 >> 2) & 1;
        const int tl_a = j15 & 3;

        unsigned int ypk[16];   // steps k<32, packed 2 f16/reg (static idx)

        // ---- park phase: chunks 0..7 (steps k=0..31) ----
        #pragma unroll
        for (int c = 0; c < 8; ++c) {
            const int tf = 4 * c;
            const int tb = T - 4 - 4 * c;
            const int row = (j15 < 8) ? (tf + tl_a) : (tb + tl_a);
            half8 ax = *(const half8*)(yb + lb_a * YSB + row * YST + quad * 8);
            f32x4v c0f = __builtin_amdgcn_mfma_f32_16x16x32_f16(ax, bf[0][0], cR, 0, 0, 0);
            f32x4v c1f = __builtin_amdgcn_mfma_f32_16x16x32_f16(ax, bf[0][1], cZ, 0, 0, 0);
            f32x4v c2f = __builtin_amdgcn_mfma_f32_16x16x32_f16(ax, bf[0][2], cNx, 0, 0, 0);
            f32x4v c0b = __builtin_amdgcn_mfma_f32_16x16x32_f16(ax, bf[1][0], cR, 0, 0, 0);
            f32x4v c1b = __builtin_amdgcn_mfma_f32_16x16x32_f16(ax, bf[1][1], cZ, 0, 0, 0);
            f32x4v c2b = __builtin_amdgcn_mfma_f32_16x16x32_f16(ax, bf[1][2], cNx, 0, 0, 0);

            #pragma unroll
            for (int s = 0; s < 4; ++s) {
                float gx0 = isf ? c0f[s] : c0b[3 - s];
                float gx1 = isf ? c1f[s] : c1b[3 - s];
                float gx2 = isf ? c2f[s] : c2b[3 - s];
                half8 a = *(const half8*)aptr;
                f32x4v d0 = __builtin_amdgcn_mfma_f32_16x16x32_f16(a, whB[0], zC, 0, 0, 0);
                f32x4v d1 = __builtin_amdgcn_mfma_f32_16x16x32_f16(a, whB[1], zC, 0, 0, 0);
                f32x4v d2 = __builtin_amdgcn_mfma_f32_16x16x32_f16(a, whB[2], cN, 0, 0, 0);
                float rg = fast_sigmoid(gx0 + d0[0]);
                float zg = fast_sigmoid(gx1 + d1[0]);
                float ng = fast_tanh(fmaf(rg, d2[0], gx2));
                float hn = fmaf(zg, hj - ng, ng);
                hj = hn;
                _Float16 hh = (_Float16)hn;
                hzb[lane] = hh;
                unsigned int hb16 = (unsigned int)__builtin_bit_cast(unsigned short, hh);
                if (s & 1) ypk[2 * c + (s >> 1)] |= hb16 << 16;
                else       ypk[2 * c + (s >> 1)]  = hb16;
            }
        }

        // ---- direct phase: chunks 8..15 (steps k=32..63), in-place writes ----
        {
            _Float16* yw = yb + lb * YSB + (isf ? 32 : 31) * YST + dir * H + j15;
            #pragma unroll 1
            for (int c = 8; c < 16; ++c) {
                const int tf = 4 * c;
                const int tb = T - 4 - 4 * c;
                const int row = (j15 < 8) ? (tf + tl_a) : (tb + tl_a);
                half8 ax = *(const half8*)(yb + lb_a * YSB + row * YST + quad * 8);
                f32x4v c0f = __builtin_amdgcn_mfma_f32_16x16x32_f16(ax, bf[0][0], cR, 0, 0, 0);
                f32x4v c1f = __builtin_amdgcn_mfma_f32_16x16x32_f16(ax, bf[0][1], cZ, 0, 0, 0);
                f32x4v c2f = __builtin_amdgcn_mfma_f32_16x16x32_f16(ax, bf[0][2], cNx, 0, 0, 0);
                f32x4v c0b = __builtin_amdgcn_mfma_f32_16x16x32_f16(ax, bf[1][0], cR, 0, 0, 0);
                f32x4v c1b = __builtin_amdgcn_mfma_f32_16x16x32_f16(ax, bf[1][1], cZ, 0, 0, 0);
                f32x4v c2b = __builtin_amdgcn_mfma_f32_16x16x32_f16(ax, bf[1][2], cNx, 0, 0, 0);

                #pragma unroll
                for (int s = 0; s < 4; ++s) {
                    float gx0 = isf ? c0f[s] : c0b[3 - s];
                    float gx1 = isf ? c1f[s] : c1b[3 - s];
                    float gx2 = isf ? c2f[s] : c2b[3 - s];
                    half8 a = *(const half8*)aptr;
                    f32x4v d0 = __builtin_amdgcn_mfma_f32_16x16x32_f16(a, whB[0], zC, 0, 0, 0);
                    f32x4v d1 = __builtin_amdgcn_mfma_f32_16x16x32_f16(a, whB[1], zC, 0, 0, 0);
                    f32x4v d2 = __builtin_amdgcn_mfma_f32_16x16x32_f16(a, whB[2], cN, 0, 0, 0);
                    float rg = fast_sigmoid(gx0 + d0[0]);
                    float zg = fast_sigmoid(gx1 + d1[0]);
                    float ng = fast_tanh(fmaf(rg, d2[0], gx2));
                    float hn = fmaf(zg, hj - ng, ng);
                    hj = hn;
                    _Float16 hh = (_Float16)hn;
                    hzb[lane] = hh;
                    *yw = hh;
                    yw += ystep;
                }
            }
        }

        // ---- dump parked half (rows 0..31 fwd / 63..32 bwd) ----
        {
            _Float16* yw = yb + lb * YSB + (isf ? 0 : (T - 1)) * YST + dir * H + j15;
            #pragma unroll
            for (int i = 0; i < 16; ++i) {
                unsigned int v = ypk[i];
                *yw = __builtin_bit_cast(_Float16, (unsigned short)(v & 0xffffu));
                yw += ystep;
                *yw = __builtin_bit_cast(_Float16, (unsigned short)(v >> 16));
                yw += ystep;
            }
        }
    }

    // ================= classifier + softmax (final y in yb) =================
    #pragma unroll
    for (int i = 0; i < 2; ++i) {
        int idx = lane + i * 64;
        int bb  = idx >> 6;
        int t   = idx & 63;
        const _Float16* yrow = yb + bb * YSB + t * YST;
        float yv[D2];
        #pragma unroll
        for (int k8 = 0; k8 < 4; ++k8) {
            half8 v = *(const half8*)(yrow + k8 * 8);
            #pragma unroll
            for (int i8 = 0; i8 < 8; ++i8) yv[k8 * 8 + i8] = (float)v[i8];
        }
        float lg[NCLS];
        #pragma unroll
        for (int c = 0; c < NCLS; ++c) {
            const float* wc = Wc + c * D2;
            float acc = bc[c];
            #pragma unroll
            for (int k = 0; k < D2; ++k) acc = fmaf(wc[k], yv[k], acc);
            lg[c] = acc;
        }
        float m = fmaxf(fmaxf(lg[0], lg[1]), fmaxf(lg[2], lg[3]));
        float e0 = __expf(lg[0] - m), e1 = __expf(lg[1] - m);
        float e2 = __expf(lg[2] - m), e3 = __expf(lg[3] - m);
        float inv = __fdividef(1.0f, e0 + e1 + e2 + e3);
        size_t bglob = (size_t)blockIdx.x * 2 + bb;
        float4 o;
        o.x = e0 * inv; o.y = e1 * inv; o.z = e2 * inv; o.w = e3 * inv;
        ((float4*)out)[bglob * T + t] = o;
    }
}

extern "C" void kernel_launch(void* const* d_in, const int* in_sizes, int n_in,
                              void* d_out, int out_size, void* d_ws, size_t ws_size,
                              hipStream_t stream) {
    const float* x   = (const float*)d_in[0];
    const float* Wi1 = (const float*)d_in[1];
    const float* Wh1 = (const float*)d_in[2];
    const float* bi1 = (const float*)d_in[3];
    const float* bh1 = (const float*)d_in[4];
    const float* Wi5 = (const float*)d_in[5];
    const float* Wh5 = (const float*)d_in[6];
    const float* bi5 = (const float*)d_in[7];
    const float* bh5 = (const float*)d_in[8];
    const float* Wc  = (const float*)d_in[9];
    const float* bc  = (const float*)d_in[10];
    float* out = (float*)d_out;

    const int B = in_sizes[0] / (T * F_IN);   // 16384
    dim3 grid(B / 2), block(64);
    hipLaunchKernelGGL(bigru_all, grid, block, 0, stream,
                       x, Wi1, Wh1, bi1, bh1, Wi5, Wh5, bi5, bh5, Wc, bc, out);
}

// Round 8
// 491.772 us; speedup vs baseline: 1.2812x; 1.0846x over previous
//
#include <hip/hip_runtime.h>

#define T 64
#define F_IN 3
#define H 16
#define G 48
#define D2 32
#define DEPTH 5
#define NCLS 4

// LDS geometry (f16 element units)
#define YST 32          // f16 per t-row (64 B rows)
#define YSB 2056        // f16 per batch elem (64*32 + 8 pad)
#define HZ_ZOFF 64      // zero block inside hzb

typedef _Float16 half8 __attribute__((ext_vector_type(8)));
typedef _Float16 half4v __attribute__((ext_vector_type(4)));
typedef float f32x4v __attribute__((ext_vector_type(4)));

__device__ __forceinline__ float fast_sigmoid(float x) {
    return __fdividef(1.0f, 1.0f + __expf(-x));
}
__device__ __forceinline__ float fast_tanh(float x) {
    return 1.0f - __fdividef(2.0f, 1.0f + __expf(2.0f * x));
}

// One wave per WG, 4 jobs: job = quad, lb = quad&1, dir = quad>>1.
// gx: per-4-step chunk, 6 MFMAs land gx[job][t][gate] in the consuming lane's
//     registers (biases added as scalars -- C splats cost 16 regs, see R7).
// gh: per step, 1 ds_read_b128 of h + 3 MFMAs (direction split in K-space).
// Occupancy: SINGLE y buffer; steps k<32 park in ypk[16] (static indices),
//     k>=32 write in-place (safe; see R7 proof). LDS ~9.4 KB.
// launch_bounds(64,3): 170-reg budget. (64,4)=128 made the allocator split
//     64 arch + 64 acc and spill ~450 MB/launch to scratch (R6/R7 FETCH_SIZE).
// Single wave per WG => lockstep => no __syncthreads() anywhere.
__global__ __launch_bounds__(64, 3) void bigru_all(
    const float* __restrict__ x,
    const float* __restrict__ Wi1, const float* __restrict__ Wh1,
    const float* __restrict__ bi1, const float* __restrict__ bh1,
    const float* __restrict__ Wi5, const float* __restrict__ Wh5,
    const float* __restrict__ bi5, const float* __restrict__ bh5,
    const float* __restrict__ Wc,  const float* __restrict__ bc,
    float* __restrict__ out)
{
    __shared__ __align__(16) _Float16 yb[2 * YSB];
    __shared__ __align__(16) _Float16 hzb[80];     // [0,64): h[job][16]; [64,72): zeros
    __shared__ __align__(16) _Float16 xs[2 * T * 4];

    const int lane = threadIdx.x;
    const int j15  = lane & 15;
    const int quad = lane >> 4;
    const int lb   = quad & 1;
    const int dir  = quad >> 1;
    const bool isf = (dir == 0);

    // ---- stage x[2][T][3] -> xs[2][T][4] (f16); zero h + zero block
    {
        const float* xg = x + (size_t)blockIdx.x * (2 * T * F_IN);
        for (int idx = lane; idx < 2 * T * F_IN; idx += 64) {
            int bb = idx / (T * F_IN);
            int r  = idx - bb * (T * F_IN);
            int tt = r / F_IN;
            int c  = r - tt * F_IN;
            xs[bb * (T * 4) + tt * 4 + c] = (_Float16)xg[idx];
        }
        hzb[lane] = (_Float16)0.0f;
        if (lane < 16) hzb[64 + lane] = (_Float16)0.0f;
    }

    // gh A-frag source (loop-invariant): lane supplies A[m=j15][k=quad*8+..7]
    const int  job_a  = j15 >> 2;
    const bool avalid = ((j15 >> 3) == 0) ? (quad < 2) : (quad >= 2);
    const _Float16* aptr = hzb + (avalid ? (job_a * 16 + (quad & 1) * 8) : HZ_ZOFF);

    const int ystep = isf ? YST : -YST;
    const f32x4v zC = {0.f, 0.f, 0.f, 0.f};

    float hj;

    // ================= layer 1 (gx scalar from xs, gh via MFMA) =============
    {
        half8 whB[3];
        {
            const float* wsrc = Wh1 + ((quad < 2) ? 0 : G * H);
            #pragma unroll
            for (int g = 0; g < 3; ++g) {
                const float* w = wsrc + (g * 16 + j15) * H + (quad & 1) * 8;
                half8 hv;
                #pragma unroll
                for (int i = 0; i < 8; ++i) hv[i] = (_Float16)w[i];
                whB[g] = hv;
            }
        }
        float wi[3][F_IN];
        float bir[3], bhr2;
        {
            const float* Wi = Wi1 + dir * (G * F_IN);
            const float* bi = bi1 + dir * G;
            const float* bh = bh1 + dir * G;
            #pragma unroll
            for (int g = 0; g < 3; ++g) {
                int row = g * H + j15;
                #pragma unroll
                for (int k = 0; k < F_IN; ++k) wi[g][k] = Wi[row * F_IN + k];
                bir[g] = bi[row] + ((g < 2) ? bh[row] : 0.0f);
            }
            bhr2 = bh[2 * H + j15];
        }
        hj = 0.0f;

        _Float16* yw = yb + lb * YSB + (isf ? 0 : (T - 1)) * YST + dir * H + j15;

        #pragma unroll 2
        for (int s = 0; s < T; ++s) {
            int t = isf ? s : (T - 1 - s);
            half4v xv = ((const half4v*)xs)[lb * T + t];
            float x0 = (float)xv[0], x1 = (float)xv[1], x2 = (float)xv[2];
            float gxr = fmaf(wi[0][2], x2, fmaf(wi[0][1], x1, fmaf(wi[0][0], x0, bir[0])));
            float gxz = fmaf(wi[1][2], x2, fmaf(wi[1][1], x1, fmaf(wi[1][0], x0, bir[1])));
            float gxn = fmaf(wi[2][2], x2, fmaf(wi[2][1], x1, fmaf(wi[2][0], x0, bir[2])));
            half8 a = *(const half8*)aptr;
            f32x4v d0 = __builtin_amdgcn_mfma_f32_16x16x32_f16(a, whB[0], zC, 0, 0, 0);
            f32x4v d1 = __builtin_amdgcn_mfma_f32_16x16x32_f16(a, whB[1], zC, 0, 0, 0);
            f32x4v d2 = __builtin_amdgcn_mfma_f32_16x16x32_f16(a, whB[2], zC, 0, 0, 0);
            float rg = fast_sigmoid(gxr + d0[0]);
            float zg = fast_sigmoid(gxz + d1[0]);
            float ng = fast_tanh(fmaf(rg, d2[0] + bhr2, gxn));
            float hn = fmaf(zg, hj - ng, ng);
            hj = hn;
            _Float16 hh = (_Float16)hn;
            hzb[lane] = hh;
            *yw = hh;       // layer 1 never reads yb -> no hazard
            yw += ystep;
        }
    }

    // ================= layers 2..6 =================
    #pragma unroll 1
    for (int l = 0; l < DEPTH; ++l) {
        // gx B-frags (both dirs)
        half8 bf[2][3];
        #pragma unroll
        for (int d = 0; d < 2; ++d) {
            #pragma unroll
            for (int g = 0; g < 3; ++g) {
                const float* w = Wi5 + ((size_t)(l * 2 + d) * G + g * 16 + j15) * D2 + quad * 8;
                half8 hv;
                #pragma unroll
                for (int i = 0; i < 8; ++i) hv[i] = (_Float16)w[i];
                bf[d][g] = hv;
            }
        }
        // gh B-frags (dir split by quad-half)
        half8 whB[3];
        {
            const float* wsrc = Wh5 + (size_t)(l * 2) * G * H + ((quad < 2) ? 0 : G * H);
            #pragma unroll
            for (int g = 0; g < 3; ++g) {
                const float* w = wsrc + (g * 16 + j15) * H + (quad & 1) * 8;
                half8 hv;
                #pragma unroll
                for (int i = 0; i < 8; ++i) hv[i] = (_Float16)w[i];
                whB[g] = hv;
            }
        }
        // own-dir biases (scalar adds, not C splats)
        float bib0, bib1, bib2, bhr2;
        {
            const float* biL = bi5 + (l * 2 + dir) * G;
            const float* bhL = bh5 + (l * 2 + dir) * G;
            bib0 = biL[j15]         + bhL[j15];
            bib1 = biL[H + j15]     + bhL[H + j15];
            bib2 = biL[2 * H + j15];
            bhr2 = bhL[2 * H + j15];
        }

        hj = 0.0f;
        hzb[lane] = (_Float16)0.0f;

        const int lb_a = (j15 >> 2) & 1;
        const int tl_a = j15 & 3;

        unsigned int ypk[16];   // steps k<32, packed 2 f16/reg (static idx)

        // ---- park phase: chunks 0..7 (steps k=0..31) ----
        #pragma unroll
        for (int c = 0; c < 8; ++c) {
            const int tf = 4 * c;
            const int tb = T - 4 - 4 * c;
            const int row = (j15 < 8) ? (tf + tl_a) : (tb + tl_a);
            half8 ax = *(const half8*)(yb + lb_a * YSB + row * YST + quad * 8);
            f32x4v c0f = __builtin_amdgcn_mfma_f32_16x16x32_f16(ax, bf[0][0], zC, 0, 0, 0);
            f32x4v c1f = __builtin_amdgcn_mfma_f32_16x16x32_f16(ax, bf[0][1], zC, 0, 0, 0);
            f32x4v c2f = __builtin_amdgcn_mfma_f32_16x16x32_f16(ax, bf[0][2], zC, 0, 0, 0);
            f32x4v c0b = __builtin_amdgcn_mfma_f32_16x16x32_f16(ax, bf[1][0], zC, 0, 0, 0);
            f32x4v c1b = __builtin_amdgcn_mfma_f32_16x16x32_f16(ax, bf[1][1], zC, 0, 0, 0);
            f32x4v c2b = __builtin_amdgcn_mfma_f32_16x16x32_f16(ax, bf[1][2], zC, 0, 0, 0);

            #pragma unroll
            for (int s = 0; s < 4; ++s) {
                float gx0 = (isf ? c0f[s] : c0b[3 - s]) + bib0;
                float gx1 = (isf ? c1f[s] : c1b[3 - s]) + bib1;
                float gx2 = (isf ? c2f[s] : c2b[3 - s]) + bib2;
                half8 a = *(const half8*)aptr;
                f32x4v d0 = __builtin_amdgcn_mfma_f32_16x16x32_f16(a, whB[0], zC, 0, 0, 0);
                f32x4v d1 = __builtin_amdgcn_mfma_f32_16x16x32_f16(a, whB[1], zC, 0, 0, 0);
                f32x4v d2 = __builtin_amdgcn_mfma_f32_16x16x32_f16(a, whB[2], zC, 0, 0, 0);
                float rg = fast_sigmoid(gx0 + d0[0]);
                float zg = fast_sigmoid(gx1 + d1[0]);
                float ng = fast_tanh(fmaf(rg, d2[0] + bhr2, gx2));
                float hn = fmaf(zg, hj - ng, ng);
                hj = hn;
                _Float16 hh = (_Float16)hn;
                hzb[lane] = hh;
                unsigned int hb16 = (unsigned int)__builtin_bit_cast(unsigned short, hh);
                if (s & 1) ypk[2 * c + (s >> 1)] |= hb16 << 16;
                else       ypk[2 * c + (s >> 1)]  = hb16;
            }
        }

        // ---- direct phase: chunks 8..15 (steps k=32..63), in-place writes ----
        {
            _Float16* yw = yb + lb * YSB + (isf ? 32 : 31) * YST + dir * H + j15;
            #pragma unroll 1
            for (int c = 8; c < 16; ++c) {
                const int tf = 4 * c;
                const int tb = T - 4 - 4 * c;
                const int row = (j15 < 8) ? (tf + tl_a) : (tb + tl_a);
                half8 ax = *(const half8*)(yb + lb_a * YSB + row * YST + quad * 8);
                f32x4v c0f = __builtin_amdgcn_mfma_f32_16x16x32_f16(ax, bf[0][0], zC, 0, 0, 0);
                f32x4v c1f = __builtin_amdgcn_mfma_f32_16x16x32_f16(ax, bf[0][1], zC, 0, 0, 0);
                f32x4v c2f = __builtin_amdgcn_mfma_f32_16x16x32_f16(ax, bf[0][2], zC, 0, 0, 0);
                f32x4v c0b = __builtin_amdgcn_mfma_f32_16x16x32_f16(ax, bf[1][0], zC, 0, 0, 0);
                f32x4v c1b = __builtin_amdgcn_mfma_f32_16x16x32_f16(ax, bf[1][1], zC, 0, 0, 0);
                f32x4v c2b = __builtin_amdgcn_mfma_f32_16x16x32_f16(ax, bf[1][2], zC, 0, 0, 0);

                #pragma unroll
                for (int s = 0; s < 4; ++s) {
                    float gx0 = (isf ? c0f[s] : c0b[3 - s]) + bib0;
                    float gx1 = (isf ? c1f[s] : c1b[3 - s]) + bib1;
                    float gx2 = (isf ? c2f[s] : c2b[3 - s]) + bib2;
                    half8 a = *(const half8*)aptr;
                    f32x4v d0 = __builtin_amdgcn_mfma_f32_16x16x32_f16(a, whB[0], zC, 0, 0, 0);
                    f32x4v d1 = __builtin_amdgcn_mfma_f32_16x16x32_f16(a, whB[1], zC, 0, 0, 0);
                    f32x4v d2 = __builtin_amdgcn_mfma_f32_16x16x32_f16(a, whB[2], zC, 0, 0, 0);
                    float rg = fast_sigmoid(gx0 + d0[0]);
                    float zg = fast_sigmoid(gx1 + d1[0]);
                    float ng = fast_tanh(fmaf(rg, d2[0] + bhr2, gx2));
                    float hn = fmaf(zg, hj - ng, ng);
                    hj = hn;
                    _Float16 hh = (_Float16)hn;
                    hzb[lane] = hh;
                    *yw = hh;
                    yw += ystep;
                }
            }
        }

        // ---- dump parked half (rows 0..31 fwd / 63..32 bwd) ----
        {
            _Float16* yw = yb + lb * YSB + (isf ? 0 : (T - 1)) * YST + dir * H + j15;
            #pragma unroll
            for (int i = 0; i < 16; ++i) {
                unsigned int v = ypk[i];
                *yw = __builtin_bit_cast(_Float16, (unsigned short)(v & 0xffffu));
                yw += ystep;
                *yw = __builtin_bit_cast(_Float16, (unsigned short)(v >> 16));
                yw += ystep;
            }
        }
    }

    // ================= classifier + softmax (final y in yb) =================
    #pragma unroll
    for (int i = 0; i < 2; ++i) {
        int idx = lane + i * 64;
        int bb  = idx >> 6;
        int t   = idx & 63;
        const _Float16* yrow = yb + bb * YSB + t * YST;
        float yv[D2];
        #pragma unroll
        for (int k8 = 0; k8 < 4; ++k8) {
            half8 v = *(const half8*)(yrow + k8 * 8);
            #pragma unroll
            for (int i8 = 0; i8 < 8; ++i8) yv[k8 * 8 + i8] = (float)v[i8];
        }
        float lg[NCLS];
        #pragma unroll
        for (int c = 0; c < NCLS; ++c) {
            const float* wc = Wc + c * D2;
            float acc = bc[c];
            #pragma unroll
            for (int k = 0; k < D2; ++k) acc = fmaf(wc[k], yv[k], acc);
            lg[c] = acc;
        }
        float m = fmaxf(fmaxf(lg[0], lg[1]), fmaxf(lg[2], lg[3]));
        float e0 = __expf(lg[0] - m), e1 = __expf(lg[1] - m);
        float e2 = __expf(lg[2] - m), e3 = __expf(lg[3] - m);
        float inv = __fdividef(1.0f, e0 + e1 + e2 + e3);
        size_t bglob = (size_t)blockIdx.x * 2 + bb;
        float4 o;
        o.x = e0 * inv; o.y = e1 * inv; o.z = e2 * inv; o.w = e3 * inv;
        ((float4*)out)[bglob * T + t] = o;
    }
}

extern "C" void kernel_launch(void* const* d_in, const int* in_sizes, int n_in,
                              void* d_out, int out_size, void* d_ws, size_t ws_size,
                              hipStream_t stream) {
    const float* x   = (const float*)d_in[0];
    const float* Wi1 = (const float*)d_in[1];
    const float* Wh1 = (const float*)d_in[2];
    const float* bi1 = (const float*)d_in[3];
    const float* bh1 = (const float*)d_in[4];
    const float* Wi5 = (const float*)d_in[5];
    const float* Wh5 = (const float*)d_in[6];
    const float* bi5 = (const float*)d_in[7];
    const float* bh5 = (const float*)d_in[8];
    const float* Wc  = (const float*)d_in[9];
    const float* bc  = (const float*)d_in[10];
    float* out = (float*)d_out;

    const int B = in_sizes[0] / (T * F_IN);   // 16384
    dim3 grid(B / 2), block(64);
    hipLaunchKernelGGL(bigru_all, grid, block, 0, stream,
                       x, Wi1, Wh1, bi1, bh1, Wi5, Wh5, bi5, bh5, Wc, bc, out);
}

// Round 9
// 365.358 us; speedup vs baseline: 1.7245x; 1.3460x over previous
//
#include <hip/hip_runtime.h>

#define T 64
#define F_IN 3
#define H 16
#define G 48
#define D2 32
#define DEPTH 5
#define NCLS 4

// LDS geometry (f16 element units)
#define YST 32          // f16 per t-row (64 B rows)
#define YSB 2056        // f16 per batch elem (64*32 + 8 pad)
#define HZ_ZOFF 64      // zero block inside hzb

typedef _Float16 half8 __attribute__((ext_vector_type(8)));
typedef _Float16 half4v __attribute__((ext_vector_type(4)));
typedef float f32x4v __attribute__((ext_vector_type(4)));

// One wave per WG, 4 jobs: job = quad, lb = quad&1, dir = quad>>1.
// gx: per-4-step chunk, 6 MFMAs land gx[job][t][gate] in the consuming lane's
//     registers; per-dir biases ride in the C splats (each lane reads only its
//     own dir's MFMA result, so wrong-dir C garbage is never consumed).
// gh: per step, 1 ds_read_b128 of h + 3 MFMAs (direction split in K-space).
// Gate math (R9): n-gate weights/biases pre-scaled by -2 so c2=-2c falls out
//     of one fma; h' = [h(1+Ec)+Ez(1-Ec)] / [(1+Ec)(1+Ez)] fuses tanh + z-blend
//     into ONE shared v_rcp -> 5 transcendentals/step (3 exp + 2 rcp) vs 6,
//     and the blend collapses to 7 cheap VALU ops. Exponent clamps (40/44)
//     keep the den/num products finite.
// launch_bounds(64,3): 170-reg budget; (64,4)=128 forced spill (R6/R7).
// Single wave per WG => lockstep => no __syncthreads() anywhere.
__global__ __launch_bounds__(64, 3) void bigru_all(
    const float* __restrict__ x,
    const float* __restrict__ Wi1, const float* __restrict__ Wh1,
    const float* __restrict__ bi1, const float* __restrict__ bh1,
    const float* __restrict__ Wi5, const float* __restrict__ Wh5,
    const float* __restrict__ bi5, const float* __restrict__ bh5,
    const float* __restrict__ Wc,  const float* __restrict__ bc,
    float* __restrict__ out)
{
    __shared__ __align__(16) _Float16 yb[2 * YSB];
    __shared__ __align__(16) _Float16 hzb[80];     // [0,64): h[job][16]; [64,72): zeros
    __shared__ __align__(16) _Float16 xs[2 * T * 4];

    const int lane = threadIdx.x;
    const int j15  = lane & 15;
    const int quad = lane >> 4;
    const int lb   = quad & 1;
    const int dir  = quad >> 1;
    const bool isf = (dir == 0);

    // ---- stage x[2][T][3] -> xs[2][T][4] (f16); zero h + zero block
    {
        const float* xg = x + (size_t)blockIdx.x * (2 * T * F_IN);
        for (int idx = lane; idx < 2 * T * F_IN; idx += 64) {
            int bb = idx / (T * F_IN);
            int r  = idx - bb * (T * F_IN);
            int tt = r / F_IN;
            int c  = r - tt * F_IN;
            xs[bb * (T * 4) + tt * 4 + c] = (_Float16)xg[idx];
        }
        hzb[lane] = (_Float16)0.0f;
        if (lane < 16) hzb[64 + lane] = (_Float16)0.0f;
    }

    // gh A-frag source (loop-invariant): lane supplies A[m=j15][k=quad*8+..7]
    const int  job_a  = j15 >> 2;
    const bool avalid = ((j15 >> 3) == 0) ? (quad < 2) : (quad >= 2);
    const _Float16* aptr = hzb + (avalid ? (job_a * 16 + (quad & 1) * 8) : HZ_ZOFF);

    const int ystep = isf ? YST : -YST;
    const f32x4v zC = {0.f, 0.f, 0.f, 0.f};

    float hj;

    // ================= layer 1 (gx scalar from xs, gh via MFMA) =============
    {
        half8 whB[3];
        {
            const float* wsrc = Wh1 + ((quad < 2) ? 0 : G * H);
            #pragma unroll
            for (int g = 0; g < 3; ++g) {
                const float scale = (g == 2) ? -2.0f : 1.0f;
                const float* w = wsrc + (g * 16 + j15) * H + (quad & 1) * 8;
                half8 hv;
                #pragma unroll
                for (int i = 0; i < 8; ++i) hv[i] = (_Float16)(scale * w[i]);
                whB[g] = hv;
            }
        }
        float wi[3][F_IN];
        float bir[3], bhn2;
        {
            const float* Wi = Wi1 + dir * (G * F_IN);
            const float* bi = bi1 + dir * G;
            const float* bh = bh1 + dir * G;
            #pragma unroll
            for (int g = 0; g < 3; ++g) {
                const float scale = (g == 2) ? -2.0f : 1.0f;
                int row = g * H + j15;
                #pragma unroll
                for (int k = 0; k < F_IN; ++k) wi[g][k] = scale * Wi[row * F_IN + k];
                bir[g] = scale * bi[row] + ((g < 2) ? bh[row] : 0.0f);
            }
            bhn2 = -2.0f * bh[2 * H + j15];
        }
        const f32x4v cN = {bhn2, bhn2, bhn2, bhn2};
        hj = 0.0f;

        _Float16* yw = yb + lb * YSB + (isf ? 0 : (T - 1)) * YST + dir * H + j15;

        #pragma unroll 2
        for (int s = 0; s < T; ++s) {
            int t = isf ? s : (T - 1 - s);
            half4v xv = ((const half4v*)xs)[lb * T + t];
            float x0 = (float)xv[0], x1 = (float)xv[1], x2 = (float)xv[2];
            float gxr = fmaf(wi[0][2], x2, fmaf(wi[0][1], x1, fmaf(wi[0][0], x0, bir[0])));
            float gxz = fmaf(wi[1][2], x2, fmaf(wi[1][1], x1, fmaf(wi[1][0], x0, bir[1])));
            float gxn = fmaf(wi[2][2], x2, fmaf(wi[2][1], x1, fmaf(wi[2][0], x0, bir[2])));
            half8 a = *(const half8*)aptr;
            f32x4v d0 = __builtin_amdgcn_mfma_f32_16x16x32_f16(a, whB[0], zC, 0, 0, 0);
            f32x4v d1 = __builtin_amdgcn_mfma_f32_16x16x32_f16(a, whB[1], zC, 0, 0, 0);
            f32x4v d2 = __builtin_amdgcn_mfma_f32_16x16x32_f16(a, whB[2], cN, 0, 0, 0);
            float av = gxr + d0[0];
            float bv = gxz + d1[0];
            float Er = __expf(fminf(40.f, -av));
            float rg = __builtin_amdgcn_rcpf(1.0f + Er);
            float c2 = fmaf(rg, d2[0], gxn);           // = -2c
            float Ez = __expf(fminf(40.f, -bv));
            float Ec = __expf(fminf(44.f, c2));        // = e^{-2c}
            float num = fmaf(hj - Ez, Ec, hj + Ez);
            float den = (1.0f + Ec) * (1.0f + Ez);
            float hn = num * __builtin_amdgcn_rcpf(den);
            hj = hn;
            _Float16 hh = (_Float16)hn;
            hzb[lane] = hh;
            *yw = hh;       // layer 1 never reads yb -> no hazard
            yw += ystep;
        }
    }

    // ================= layers 2..6 =================
    #pragma unroll 1
    for (int l = 0; l < DEPTH; ++l) {
        // gx B-frags (both dirs); n-gate scaled by -2
        half8 bf[2][3];
        #pragma unroll
        for (int d = 0; d < 2; ++d) {
            #pragma unroll
            for (int g = 0; g < 3; ++g) {
                const float scale = (g == 2) ? -2.0f : 1.0f;
                const float* w = Wi5 + ((size_t)(l * 2 + d) * G + g * 16 + j15) * D2 + quad * 8;
                half8 hv;
                #pragma unroll
                for (int i = 0; i < 8; ++i) hv[i] = (_Float16)(scale * w[i]);
                bf[d][g] = hv;
            }
        }
        // gh B-frags (dir split by quad-half); n-gate scaled by -2
        half8 whB[3];
        {
            const float* wsrc = Wh5 + (size_t)(l * 2) * G * H + ((quad < 2) ? 0 : G * H);
            #pragma unroll
            for (int g = 0; g < 3; ++g) {
                const float scale = (g == 2) ? -2.0f : 1.0f;
                const float* w = wsrc + (g * 16 + j15) * H + (quad & 1) * 8;
                half8 hv;
                #pragma unroll
                for (int i = 0; i < 8; ++i) hv[i] = (_Float16)(scale * w[i]);
                whB[g] = hv;
            }
        }
        // own-dir biases -> C splats (r,z: bi+bh; n: -2*bi and -2*bh)
        float bib0, bib1, bib2, bhn2;
        {
            const float* biL = bi5 + (l * 2 + dir) * G;
            const float* bhL = bh5 + (l * 2 + dir) * G;
            bib0 = biL[j15]         + bhL[j15];
            bib1 = biL[H + j15]     + bhL[H + j15];
            bib2 = -2.0f * biL[2 * H + j15];
            bhn2 = -2.0f * bhL[2 * H + j15];
        }
        const f32x4v cR  = {bib0, bib0, bib0, bib0};
        const f32x4v cZ  = {bib1, bib1, bib1, bib1};
        const f32x4v cNx = {bib2, bib2, bib2, bib2};
        const f32x4v cN  = {bhn2, bhn2, bhn2, bhn2};

        hj = 0.0f;
        hzb[lane] = (_Float16)0.0f;

        const int lb_a = (j15 >> 2) & 1;
        const int tl_a = j15 & 3;

        unsigned int ypk[16];   // steps k<32, packed 2 f16/reg (static idx)

        // ---- park phase: chunks 0..7 (steps k=0..31) ----
        #pragma unroll
        for (int c = 0; c < 8; ++c) {
            const int tf = 4 * c;
            const int tb = T - 4 - 4 * c;
            const int row = (j15 < 8) ? (tf + tl_a) : (tb + tl_a);
            half8 ax = *(const half8*)(yb + lb_a * YSB + row * YST + quad * 8);
            f32x4v c0f = __builtin_amdgcn_mfma_f32_16x16x32_f16(ax, bf[0][0], cR, 0, 0, 0);
            f32x4v c1f = __builtin_amdgcn_mfma_f32_16x16x32_f16(ax, bf[0][1], cZ, 0, 0, 0);
            f32x4v c2f = __builtin_amdgcn_mfma_f32_16x16x32_f16(ax, bf[0][2], cNx, 0, 0, 0);
            f32x4v c0b = __builtin_amdgcn_mfma_f32_16x16x32_f16(ax, bf[1][0], cR, 0, 0, 0);
            f32x4v c1b = __builtin_amdgcn_mfma_f32_16x16x32_f16(ax, bf[1][1], cZ, 0, 0, 0);
            f32x4v c2b = __builtin_amdgcn_mfma_f32_16x16x32_f16(ax, bf[1][2], cNx, 0, 0, 0);

            #pragma unroll
            for (int s = 0; s < 4; ++s) {
                float gx0 = isf ? c0f[s] : c0b[3 - s];
                float gx1 = isf ? c1f[s] : c1b[3 - s];
                float gx2 = isf ? c2f[s] : c2b[3 - s];
                half8 a = *(const half8*)aptr;
                f32x4v d0 = __builtin_amdgcn_mfma_f32_16x16x32_f16(a, whB[0], zC, 0, 0, 0);
                f32x4v d1 = __builtin_amdgcn_mfma_f32_16x16x32_f16(a, whB[1], zC, 0, 0, 0);
                f32x4v d2 = __builtin_amdgcn_mfma_f32_16x16x32_f16(a, whB[2], cN, 0, 0, 0);
                float av = gx0 + d0[0];
                float bv = gx1 + d1[0];
                float Er = __expf(fminf(40.f, -av));
                float rg = __builtin_amdgcn_rcpf(1.0f + Er);
                float c2 = fmaf(rg, d2[0], gx2);
                float Ez = __expf(fminf(40.f, -bv));
                float Ec = __expf(fminf(44.f, c2));
                float num = fmaf(hj - Ez, Ec, hj + Ez);
                float den = (1.0f + Ec) * (1.0f + Ez);
                float hn = num * __builtin_amdgcn_rcpf(den);
                hj = hn;
                _Float16 hh = (_Float16)hn;
                hzb[lane] = hh;
                unsigned int hb16 = (unsigned int)__builtin_bit_cast(unsigned short, hh);
                if (s & 1) ypk[2 * c + (s >> 1)] |= hb16 << 16;
                else       ypk[2 * c + (s >> 1)]  = hb16;
            }
        }

        // ---- direct phase: chunks 8..15 (steps k=32..63), in-place writes ----
        {
            _Float16* yw = yb + lb * YSB + (isf ? 32 : 31) * YST + dir * H + j15;
            #pragma unroll 1
            for (int c = 8; c < 16; ++c) {
                const int tf = 4 * c;
                const int tb = T - 4 - 4 * c;
                const int row = (j15 < 8) ? (tf + tl_a) : (tb + tl_a);
                half8 ax = *(const half8*)(yb + lb_a * YSB + row * YST + quad * 8);
                f32x4v c0f = __builtin_amdgcn_mfma_f32_16x16x32_f16(ax, bf[0][0], cR, 0, 0, 0);
                f32x4v c1f = __builtin_amdgcn_mfma_f32_16x16x32_f16(ax, bf[0][1], cZ, 0, 0, 0);
                f32x4v c2f = __builtin_amdgcn_mfma_f32_16x16x32_f16(ax, bf[0][2], cNx, 0, 0, 0);
                f32x4v c0b = __builtin_amdgcn_mfma_f32_16x16x32_f16(ax, bf[1][0], cR, 0, 0, 0);
                f32x4v c1b = __builtin_amdgcn_mfma_f32_16x16x32_f16(ax, bf[1][1], cZ, 0, 0, 0);
                f32x4v c2b = __builtin_amdgcn_mfma_f32_16x16x32_f16(ax, bf[1][2], cNx, 0, 0, 0);

                #pragma unroll
                for (int s = 0; s < 4; ++s) {
                    float gx0 = isf ? c0f[s] : c0b[3 - s];
                    float gx1 = isf ? c1f[s] : c1b[3 - s];
                    float gx2 = isf ? c2f[s] : c2b[3 - s];
                    half8 a = *(const half8*)aptr;
                    f32x4v d0 = __builtin_amdgcn_mfma_f32_16x16x32_f16(a, whB[0], zC, 0, 0, 0);
                    f32x4v d1 = __builtin_amdgcn_mfma_f32_16x16x32_f16(a, whB[1], zC, 0, 0, 0);
                    f32x4v d2 = __builtin_amdgcn_mfma_f32_16x16x32_f16(a, whB[2], cN, 0, 0, 0);
                    float av = gx0 + d0[0];
                    float bv = gx1 + d1[0];
                    float Er = __expf(fminf(40.f, -av));
                    float rg = __builtin_amdgcn_rcpf(1.0f + Er);
                    float c2 = fmaf(rg, d2[0], gx2);
                    float Ez = __expf(fminf(40.f, -bv));
                    float Ec = __expf(fminf(44.f, c2));
                    float num = fmaf(hj - Ez, Ec, hj + Ez);
                    float den = (1.0f + Ec) * (1.0f + Ez);
                    float hn = num * __builtin_amdgcn_rcpf(den);
                    hj = hn;
                    _Float16 hh = (_Float16)hn;
                    hzb[lane] = hh;
                    *yw = hh;
                    yw += ystep;
                }
            }
        }

        // ---- dump parked half (rows 0..31 fwd / 63..32 bwd) ----
        {
            _Float16* yw = yb + lb * YSB + (isf ? 0 : (T - 1)) * YST + dir * H + j15;
            #pragma unroll
            for (int i = 0; i < 16; ++i) {
                unsigned int v = ypk[i];
                *yw = __builtin_bit_cast(_Float16, (unsigned short)(v & 0xffffu));
                yw += ystep;
                *yw = __builtin_bit_cast(_Float16, (unsigned short)(v >> 16));
                yw += ystep;
            }
        }
    }

    // ================= classifier + softmax (final y in yb) =================
    #pragma unroll
    for (int i = 0; i < 2; ++i) {
        int idx = lane + i * 64;
        int bb  = idx >> 6;
        int t   = idx & 63;
        const _Float16* yrow = yb + bb * YSB + t * YST;
        float yv[D2];
        #pragma unroll
        for (int k8 = 0; k8 < 4; ++k8) {
            half8 v = *(const half8*)(yrow + k8 * 8);
            #pragma unroll
            for (int i8 = 0; i8 < 8; ++i8) yv[k8 * 8 + i8] = (float)v[i8];
        }
        float lg[NCLS];
        #pragma unroll
        for (int c = 0; c < NCLS; ++c) {
            const float* wc = Wc + c * D2;
            float acc = bc[c];
            #pragma unroll
            for (int k = 0; k < D2; ++k) acc = fmaf(wc[k], yv[k], acc);
            lg[c] = acc;
        }
        float m = fmaxf(fmaxf(lg[0], lg[1]), fmaxf(lg[2], lg[3]));
        float e0 = __expf(lg[0] - m), e1 = __expf(lg[1] - m);
        float e2 = __expf(lg[2] - m), e3 = __expf(lg[3] - m);
        float inv = __builtin_amdgcn_rcpf(e0 + e1 + e2 + e3);
        size_t bglob = (size_t)blockIdx.x * 2 + bb;
        float4 o;
        o.x = e0 * inv; o.y = e1 * inv; o.z = e2 * inv; o.w = e3 * inv;
        ((float4*)out)[bglob * T + t] = o;
    }
}

extern "C" void kernel_launch(void* const* d_in, const int* in_sizes, int n_in,
                              void* d_out, int out_size, void* d_ws, size_t ws_size,
                              hipStream_t stream) {
    const float* x   = (const float*)d_in[0];
    const float* Wi1 = (const float*)d_in[1];
    const float* Wh1 = (const float*)d_in[2];
    const float* bi1 = (const float*)d_in[3];
    const float* bh1 = (const float*)d_in[4];
    const float* Wi5 = (const float*)d_in[5];
    const float* Wh5 = (const float*)d_in[6];
    const float* bi5 = (const float*)d_in[7];
    const float* bh5 = (const float*)d_in[8];
    const float* Wc  = (const float*)d_in[9];
    const float* bc  = (const float*)d_in[10];
    float* out = (float*)d_out;

    const int B = in_sizes[0] / (T * F_IN);   // 16384
    dim3 grid(B / 2), block(64);
    hipLaunchKernelGGL(bigru_all, grid, block, 0, stream,
                       x, Wi1, Wh1, bi1, bh1, Wi5, Wh5, bi5, bh5, Wc, bc, out);
}

// Round 10
// 364.029 us; speedup vs baseline: 1.7308x; 1.0037x over previous
//
#include <hip/hip_runtime.h>

#define T 64
#define F_IN 3
#define H 16
#define G 48
#define D2 32
#define DEPTH 5
#define NCLS 4

// LDS geometry (f16 element units)
#define YST 32          // f16 per t-row (64 B rows)
#define YSB 2048        // f16 per batch elem (no pad -- LDS must fit 8.2 KB)
#define HZ_ZOFF 64      // zero block inside hzb

typedef _Float16 half8 __attribute__((ext_vector_type(8)));
typedef _Float16 half4v __attribute__((ext_vector_type(4)));
typedef float f32x4v __attribute__((ext_vector_type(4)));

// One wave per WG, 4 jobs: job = quad, lb = quad&1, dir = quad>>1.
// gx: per-4-step chunk, 6 MFMAs land gx[job][t][gate] in the consuming lane's
//     registers; per-dir biases ride in the C splats.
// gh: per step, 1 ds_read_b128 of h + 3 MFMAs (direction split in K-space).
// Gate math (R9): n-gate pre-scaled by -2; h' = [h(1+Ec)+Ez(1-Ec)] /
//     [(1+Ec)(1+Ez)] -> 5 transcendentals/step (3 exp + 2 rcp).
// R10: LDS diet to test the ~10 WG/CU residency cap. xs staging removed
//     (layer 1 reads x from global; loads are recurrence-independent and
//     hoisted by unroll), yb pad dropped -> declared LDS ~8.35 KB.
// launch_bounds(64,3): 170-reg budget; (64,4)=128 forced spill (R6/R7).
// Single wave per WG => lockstep => no __syncthreads() anywhere.
__global__ __launch_bounds__(64, 3) void bigru_all(
    const float* __restrict__ x,
    const float* __restrict__ Wi1, const float* __restrict__ Wh1,
    const float* __restrict__ bi1, const float* __restrict__ bh1,
    const float* __restrict__ Wi5, const float* __restrict__ Wh5,
    const float* __restrict__ bi5, const float* __restrict__ bh5,
    const float* __restrict__ Wc,  const float* __restrict__ bc,
    float* __restrict__ out)
{
    __shared__ __align__(16) _Float16 yb[2 * YSB];
    __shared__ __align__(16) _Float16 hzb[80];     // [0,64): h[job][16]; [64,72): zeros

    const int lane = threadIdx.x;
    const int j15  = lane & 15;
    const int quad = lane >> 4;
    const int lb   = quad & 1;
    const int dir  = quad >> 1;
    const bool isf = (dir == 0);

    hzb[lane] = (_Float16)0.0f;
    if (lane < 16) hzb[64 + lane] = (_Float16)0.0f;

    // gh A-frag source (loop-invariant): lane supplies A[m=j15][k=quad*8+..7]
    const int  job_a  = j15 >> 2;
    const bool avalid = ((j15 >> 3) == 0) ? (quad < 2) : (quad >= 2);
    const _Float16* aptr = hzb + (avalid ? (job_a * 16 + (quad & 1) * 8) : HZ_ZOFF);

    const int ystep = isf ? YST : -YST;
    const f32x4v zC = {0.f, 0.f, 0.f, 0.f};

    float hj;

    // ================= layer 1 (gx scalar from global x, gh via MFMA) =======
    {
        half8 whB[3];
        {
            const float* wsrc = Wh1 + ((quad < 2) ? 0 : G * H);
            #pragma unroll
            for (int g = 0; g < 3; ++g) {
                const float scale = (g == 2) ? -2.0f : 1.0f;
                const float* w = wsrc + (g * 16 + j15) * H + (quad & 1) * 8;
                half8 hv;
                #pragma unroll
                for (int i = 0; i < 8; ++i) hv[i] = (_Float16)(scale * w[i]);
                whB[g] = hv;
            }
        }
        float wi[3][F_IN];
        float bir[3], bhn2;
        {
            const float* Wi = Wi1 + dir * (G * F_IN);
            const float* bi = bi1 + dir * G;
            const float* bh = bh1 + dir * G;
            #pragma unroll
            for (int g = 0; g < 3; ++g) {
                const float scale = (g == 2) ? -2.0f : 1.0f;
                int row = g * H + j15;
                #pragma unroll
                for (int k = 0; k < F_IN; ++k) wi[g][k] = scale * Wi[row * F_IN + k];
                bir[g] = scale * bi[row] + ((g < 2) ? bh[row] : 0.0f);
            }
            bhn2 = -2.0f * bh[2 * H + j15];
        }
        const f32x4v cN = {bhn2, bhn2, bhn2, bhn2};
        hj = 0.0f;

        const float* xg = x + (size_t)blockIdx.x * (2 * T * F_IN) + (size_t)lb * (T * F_IN);
        _Float16* yw = yb + lb * YSB + (isf ? 0 : (T - 1)) * YST + dir * H + j15;

        #pragma unroll 4
        for (int s = 0; s < T; ++s) {
            int t = isf ? s : (T - 1 - s);
            const float* xp = xg + t * F_IN;   // job-uniform -> L1 broadcast
            float x0 = xp[0], x1 = xp[1], x2 = xp[2];
            float gxr = fmaf(wi[0][2], x2, fmaf(wi[0][1], x1, fmaf(wi[0][0], x0, bir[0])));
            float gxz = fmaf(wi[1][2], x2, fmaf(wi[1][1], x1, fmaf(wi[1][0], x0, bir[1])));
            float gxn = fmaf(wi[2][2], x2, fmaf(wi[2][1], x1, fmaf(wi[2][0], x0, bir[2])));
            half8 a = *(const half8*)aptr;
            f32x4v d0 = __builtin_amdgcn_mfma_f32_16x16x32_f16(a, whB[0], zC, 0, 0, 0);
            f32x4v d1 = __builtin_amdgcn_mfma_f32_16x16x32_f16(a, whB[1], zC, 0, 0, 0);
            f32x4v d2 = __builtin_amdgcn_mfma_f32_16x16x32_f16(a, whB[2], cN, 0, 0, 0);
            float av = gxr + d0[0];
            float bv = gxz + d1[0];
            float Er = __expf(fminf(40.f, -av));
            float rg = __builtin_amdgcn_rcpf(1.0f + Er);
            float c2 = fmaf(rg, d2[0], gxn);           // = -2c
            float Ez = __expf(fminf(40.f, -bv));
            float Ec = __expf(fminf(44.f, c2));        // = e^{-2c}
            float num = fmaf(hj - Ez, Ec, hj + Ez);
            float den = (1.0f + Ec) * (1.0f + Ez);
            float hn = num * __builtin_amdgcn_rcpf(den);
            hj = hn;
            _Float16 hh = (_Float16)hn;
            hzb[lane] = hh;
            *yw = hh;       // layer 1 never reads yb -> no hazard
            yw += ystep;
        }
    }

    // ================= layers 2..6 =================
    #pragma unroll 1
    for (int l = 0; l < DEPTH; ++l) {
        // gx B-frags (both dirs); n-gate scaled by -2
        half8 bf[2][3];
        #pragma unroll
        for (int d = 0; d < 2; ++d) {
            #pragma unroll
            for (int g = 0; g < 3; ++g) {
                const float scale = (g == 2) ? -2.0f : 1.0f;
                const float* w = Wi5 + ((size_t)(l * 2 + d) * G + g * 16 + j15) * D2 + quad * 8;
                half8 hv;
                #pragma unroll
                for (int i = 0; i < 8; ++i) hv[i] = (_Float16)(scale * w[i]);
                bf[d][g] = hv;
            }
        }
        // gh B-frags (dir split by quad-half); n-gate scaled by -2
        half8 whB[3];
        {
            const float* wsrc = Wh5 + (size_t)(l * 2) * G * H + ((quad < 2) ? 0 : G * H);
            #pragma unroll
            for (int g = 0; g < 3; ++g) {
                const float scale = (g == 2) ? -2.0f : 1.0f;
                const float* w = wsrc + (g * 16 + j15) * H + (quad & 1) * 8;
                half8 hv;
                #pragma unroll
                for (int i = 0; i < 8; ++i) hv[i] = (_Float16)(scale * w[i]);
                whB[g] = hv;
            }
        }
        // own-dir biases -> C splats (r,z: bi+bh; n: -2*bi and -2*bh)
        float bib0, bib1, bib2, bhn2;
        {
            const float* biL = bi5 + (l * 2 + dir) * G;
            const float* bhL = bh5 + (l * 2 + dir) * G;
            bib0 = biL[j15]         + bhL[j15];
            bib1 = biL[H + j15]     + bhL[H + j15];
            bib2 = -2.0f * biL[2 * H + j15];
            bhn2 = -2.0f * bhL[2 * H + j15];
        }
        const f32x4v cR  = {bib0, bib0, bib0, bib0};
        const f32x4v cZ  = {bib1, bib1, bib1, bib1};
        const f32x4v cNx = {bib2, bib2, bib2, bib2};
        const f32x4v cN  = {bhn2, bhn2, bhn2, bhn2};

        hj = 0.0f;
        hzb[lane] = (_Float16)0.0f;

        const int lb_a = (j15 >> 2) & 1;
        const int tl_a = j15 & 3;

        unsigned int ypk[16];   // steps k<32, packed 2 f16/reg (static idx)

        // ---- park phase: chunks 0..7 (steps k=0..31) ----
        #pragma unroll
        for (int c = 0; c < 8; ++c) {
            const int tf = 4 * c;
            const int tb = T - 4 - 4 * c;
            const int row = (j15 < 8) ? (tf + tl_a) : (tb + tl_a);
            half8 ax = *(const half8*)(yb + lb_a * YSB + row * YST + quad * 8);
            f32x4v c0f = __builtin_amdgcn_mfma_f32_16x16x32_f16(ax, bf[0][0], cR, 0, 0, 0);
            f32x4v c1f = __builtin_amdgcn_mfma_f32_16x16x32_f16(ax, bf[0][1], cZ, 0, 0, 0);
            f32x4v c2f = __builtin_amdgcn_mfma_f32_16x16x32_f16(ax, bf[0][2], cNx, 0, 0, 0);
            f32x4v c0b = __builtin_amdgcn_mfma_f32_16x16x32_f16(ax, bf[1][0], cR, 0, 0, 0);
            f32x4v c1b = __builtin_amdgcn_mfma_f32_16x16x32_f16(ax, bf[1][1], cZ, 0, 0, 0);
            f32x4v c2b = __builtin_amdgcn_mfma_f32_16x16x32_f16(ax, bf[1][2], cNx, 0, 0, 0);

            #pragma unroll
            for (int s = 0; s < 4; ++s) {
                float gx0 = isf ? c0f[s] : c0b[3 - s];
                float gx1 = isf ? c1f[s] : c1b[3 - s];
                float gx2 = isf ? c2f[s] : c2b[3 - s];
                half8 a = *(const half8*)aptr;
                f32x4v d0 = __builtin_amdgcn_mfma_f32_16x16x32_f16(a, whB[0], zC, 0, 0, 0);
                f32x4v d1 = __builtin_amdgcn_mfma_f32_16x16x32_f16(a, whB[1], zC, 0, 0, 0);
                f32x4v d2 = __builtin_amdgcn_mfma_f32_16x16x32_f16(a, whB[2], cN, 0, 0, 0);
                float av = gx0 + d0[0];
                float bv = gx1 + d1[0];
                float Er = __expf(fminf(40.f, -av));
                float rg = __builtin_amdgcn_rcpf(1.0f + Er);
                float c2 = fmaf(rg, d2[0], gx2);
                float Ez = __expf(fminf(40.f, -bv));
                float Ec = __expf(fminf(44.f, c2));
                float num = fmaf(hj - Ez, Ec, hj + Ez);
                float den = (1.0f + Ec) * (1.0f + Ez);
                float hn = num * __builtin_amdgcn_rcpf(den);
                hj = hn;
                _Float16 hh = (_Float16)hn;
                hzb[lane] = hh;
                unsigned int hb16 = (unsigned int)__builtin_bit_cast(unsigned short, hh);
                if (s & 1) ypk[2 * c + (s >> 1)] |= hb16 << 16;
                else       ypk[2 * c + (s >> 1)]  = hb16;
            }
        }

        // ---- direct phase: chunks 8..15 (steps k=32..63), in-place writes ----
        {
            _Float16* yw = yb + lb * YSB + (isf ? 32 : 31) * YST + dir * H + j15;
            #pragma unroll 1
            for (int c = 8; c < 16; ++c) {
                const int tf = 4 * c;
                const int tb = T - 4 - 4 * c;
                const int row = (j15 < 8) ? (tf + tl_a) : (tb + tl_a);
                half8 ax = *(const half8*)(yb + lb_a * YSB + row * YST + quad * 8);
                f32x4v c0f = __builtin_amdgcn_mfma_f32_16x16x32_f16(ax, bf[0][0], cR, 0, 0, 0);
                f32x4v c1f = __builtin_amdgcn_mfma_f32_16x16x32_f16(ax, bf[0][1], cZ, 0, 0, 0);
                f32x4v c2f = __builtin_amdgcn_mfma_f32_16x16x32_f16(ax, bf[0][2], cNx, 0, 0, 0);
                f32x4v c0b = __builtin_amdgcn_mfma_f32_16x16x32_f16(ax, bf[1][0], cR, 0, 0, 0);
                f32x4v c1b = __builtin_amdgcn_mfma_f32_16x16x32_f16(ax, bf[1][1], cZ, 0, 0, 0);
                f32x4v c2b = __builtin_amdgcn_mfma_f32_16x16x32_f16(ax, bf[1][2], cNx, 0, 0, 0);

                #pragma unroll
                for (int s = 0; s < 4; ++s) {
                    float gx0 = isf ? c0f[s] : c0b[3 - s];
                    float gx1 = isf ? c1f[s] : c1b[3 - s];
                    float gx2 = isf ? c2f[s] : c2b[3 - s];
                    half8 a = *(const half8*)aptr;
                    f32x4v d0 = __builtin_amdgcn_mfma_f32_16x16x32_f16(a, whB[0], zC, 0, 0, 0);
                    f32x4v d1 = __builtin_amdgcn_mfma_f32_16x16x32_f16(a, whB[1], zC, 0, 0, 0);
                    f32x4v d2 = __builtin_amdgcn_mfma_f32_16x16x32_f16(a, whB[2], cN, 0, 0, 0);
                    float av = gx0 + d0[0];
                    float bv = gx1 + d1[0];
                    float Er = __expf(fminf(40.f, -av));
                    float rg = __builtin_amdgcn_rcpf(1.0f + Er);
                    float c2 = fmaf(rg, d2[0], gx2);
                    float Ez = __expf(fminf(40.f, -bv));
                    float Ec = __expf(fminf(44.f, c2));
                    float num = fmaf(hj - Ez, Ec, hj + Ez);
                    float den = (1.0f + Ec) * (1.0f + Ez);
                    float hn = num * __builtin_amdgcn_rcpf(den);
                    hj = hn;
                    _Float16 hh = (_Float16)hn;
                    hzb[lane] = hh;
                    *yw = hh;
                    yw += ystep;
                }
            }
        }

        // ---- dump parked half (rows 0..31 fwd / 63..32 bwd) ----
        {
            _Float16* yw = yb + lb * YSB + (isf ? 0 : (T - 1)) * YST + dir * H + j15;
            #pragma unroll
            for (int i = 0; i < 16; ++i) {
                unsigned int v = ypk[i];
                *yw = __builtin_bit_cast(_Float16, (unsigned short)(v & 0xffffu));
                yw += ystep;
                *yw = __builtin_bit_cast(_Float16, (unsigned short)(v >> 16));
                yw += ystep;
            }
        }
    }

    // ================= classifier + softmax (final y in yb) =================
    #pragma unroll
    for (int i = 0; i < 2; ++i) {
        int idx = lane + i * 64;
        int bb  = idx >> 6;
        int t   = idx & 63;
        const _Float16* yrow = yb + bb * YSB + t * YST;
        float yv[D2];
        #pragma unroll
        for (int k8 = 0; k8 < 4; ++k8) {
            half8 v = *(const half8*)(yrow + k8 * 8);
            #pragma unroll
            for (int i8 = 0; i8 < 8; ++i8) yv[k8 * 8 + i8] = (float)v[i8];
        }
        float lg[NCLS];
        #pragma unroll
        for (int c = 0; c < NCLS; ++c) {
            const float* wc = Wc + c * D2;
            float acc = bc[c];
            #pragma unroll
            for (int k = 0; k < D2; ++k) acc = fmaf(wc[k], yv[k], acc);
            lg[c] = acc;
        }
        float m = fmaxf(fmaxf(lg[0], lg[1]), fmaxf(lg[2], lg[3]));
        float e0 = __expf(lg[0] - m), e1 = __expf(lg[1] - m);
        float e2 = __expf(lg[2] - m), e3 = __expf(lg[3] - m);
        float inv = __builtin_amdgcn_rcpf(e0 + e1 + e2 + e3);
        size_t bglob = (size_t)blockIdx.x * 2 + bb;
        float4 o;
        o.x = e0 * inv; o.y = e1 * inv; o.z = e2 * inv; o.w = e3 * inv;
        ((float4*)out)[bglob * T + t] = o;
    }
}

extern "C" void kernel_launch(void* const* d_in, const int* in_sizes, int n_in,
                              void* d_out, int out_size, void* d_ws, size_t ws_size,
                              hipStream_t stream) {
    const float* x   = (const float*)d_in[0];
    const float* Wi1 = (const float*)d_in[1];
    const float* Wh1 = (const float*)d_in[2];
    const float* bi1 = (const float*)d_in[3];
    const float* bh1 = (const float*)d_in[4];
    const float* Wi5 = (const float*)d_in[5];
    const float* Wh5 = (const float*)d_in[6];
    const float* bi5 = (const float*)d_in[7];
    const float* bh5 = (const float*)d_in[8];
    const float* Wc  = (const float*)d_in[9];
    const float* bc  = (const float*)d_in[10];
    float* out = (float*)d_out;

    const int B = in_sizes[0] / (T * F_IN);   // 16384
    dim3 grid(B / 2), block(64);
    hipLaunchKernelGGL(bigru_all, grid, block, 0, stream,
                       x, Wi1, Wh1, bi1, bh1, Wi5, Wh5, bi5, bh5, Wc, bc, out);
}

// Round 11
// 349.637 us; speedup vs baseline: 1.8021x; 1.0412x over previous
//
#include <hip/hip_runtime.h>

#define T 64
#define F_IN 3
#define H 16
#define G 48
#define D2 32
#define DEPTH 5
#define NCLS 4
#define L2E 1.44269504f

// LDS geometry (f16 element units)
#define YST 32          // f16 per t-row (64 B rows)
#define YSB 2048        // f16 per batch elem
#define HZ_ZOFF 64      // zero block inside hzb (16 B)

typedef _Float16 half8 __attribute__((ext_vector_type(8)));
typedef float f32x4v __attribute__((ext_vector_type(4)));

__device__ __forceinline__ float fexp2(float x) { return __builtin_amdgcn_exp2f(x); }
__device__ __forceinline__ float frcp(float x)  { return __builtin_amdgcn_rcpf(x); }

// One wave per WG, 4 jobs: job = quad, lb = quad&1, dir = quad>>1.
// All gate pre-activations carry a log2(e) scale folded into weights/biases,
// so exp() is raw v_exp_f32 (no mul). n-gate additionally scaled by -2 (R9).
// gx (R11): ONE K-split MFMA chain per gate instead of fwd+bwd pairs:
//   A rows 0..7 = fwd y rows (k<16 live, k>=16 zero), rows 8..15 = bwd y rows
//   (k>=16 live); B packs Wi_fwd in k<16, Wi_bwd in k>=16; chained over the
//   two 16-dim halves of y (6 MFMAs/chunk). Bwd A rows mirrored in t so
//   C reg s == step s for BOTH dirs -> zero per-step selects. Biases in C.
// gh: per step, 1 ds_read_b128 of h + 3 MFMAs (direction split in K-space).
// h' = [h(1+Ec)+Ez(1-Ec)] / [(1+Ec)(1+Ez)], 5 transcendentals/step.
// Occupancy: register-bound at launch_bounds(64,3) = 3 waves/SIMD (R10).
// Single wave per WG => lockstep => no __syncthreads() anywhere.
__global__ __launch_bounds__(64, 3) void bigru_all(
    const float* __restrict__ x,
    const float* __restrict__ Wi1, const float* __restrict__ Wh1,
    const float* __restrict__ bi1, const float* __restrict__ bh1,
    const float* __restrict__ Wi5, const float* __restrict__ Wh5,
    const float* __restrict__ bi5, const float* __restrict__ bh5,
    const float* __restrict__ Wc,  const float* __restrict__ bc,
    float* __restrict__ out)
{
    __shared__ __align__(16) _Float16 yb[2 * YSB];
    __shared__ __align__(16) _Float16 hzb[80];     // [0,64): h[job][16]; [64,72): zeros

    const int lane = threadIdx.x;
    const int j15  = lane & 15;
    const int quad = lane >> 4;
    const int lb   = quad & 1;
    const int dir  = quad >> 1;
    const bool isf = (dir == 0);

    hzb[lane] = (_Float16)0.0f;
    if (lane < 16) hzb[64 + lane] = (_Float16)0.0f;

    // gh A-frag source (loop-invariant)
    const int  job_a  = j15 >> 2;
    const bool avalid = ((j15 >> 3) == 0) ? (quad < 2) : (quad >= 2);
    const _Float16* aptr = hzb + (avalid ? (job_a * 16 + (quad & 1) * 8) : HZ_ZOFF);

    const int ystep = isf ? YST : -YST;
    const f32x4v zC = {0.f, 0.f, 0.f, 0.f};
    const int klo = (quad & 1) * 8;        // k-offset within a 16-dim half
    const int bdir = (quad < 2) ? 0 : 1;   // which dir's weights this lane's B/A k-half serves

    float hj;

    // ================= layer 1 (gx scalar from global x, gh via MFMA) =======
    {
        half8 whB[3];
        {
            const float* wsrc = Wh1 + bdir * (G * H);
            #pragma unroll
            for (int g = 0; g < 3; ++g) {
                const float scale = (g == 2) ? (-2.0f * L2E) : L2E;
                const float* w = wsrc + (g * 16 + j15) * H + klo;
                half8 hv;
                #pragma unroll
                for (int i = 0; i < 8; ++i) hv[i] = (_Float16)(scale * w[i]);
                whB[g] = hv;
            }
        }
        float wi[3][F_IN];
        float bir[3], bhn2;
        {
            const float* Wi = Wi1 + dir * (G * F_IN);
            const float* bi = bi1 + dir * G;
            const float* bh = bh1 + dir * G;
            #pragma unroll
            for (int g = 0; g < 3; ++g) {
                const float scale = (g == 2) ? (-2.0f * L2E) : L2E;
                int row = g * H + j15;
                #pragma unroll
                for (int k = 0; k < F_IN; ++k) wi[g][k] = scale * Wi[row * F_IN + k];
                bir[g] = scale * bi[row] + ((g < 2) ? (L2E * bh[row]) : 0.0f);
            }
            bhn2 = -2.0f * L2E * bh[2 * H + j15];
        }
        const f32x4v cN = {bhn2, bhn2, bhn2, bhn2};
        hj = 0.0f;

        const float* xg = x + (size_t)blockIdx.x * (2 * T * F_IN) + (size_t)lb * (T * F_IN);
        _Float16* yw = yb + lb * YSB + (isf ? 0 : (T - 1)) * YST + dir * H + j15;

        #pragma unroll 4
        for (int s = 0; s < T; ++s) {
            int t = isf ? s : (T - 1 - s);
            const float* xp = xg + t * F_IN;
            float x0 = xp[0], x1 = xp[1], x2 = xp[2];
            float gxr = fmaf(wi[0][2], x2, fmaf(wi[0][1], x1, fmaf(wi[0][0], x0, bir[0])));
            float gxz = fmaf(wi[1][2], x2, fmaf(wi[1][1], x1, fmaf(wi[1][0], x0, bir[1])));
            float gxn = fmaf(wi[2][2], x2, fmaf(wi[2][1], x1, fmaf(wi[2][0], x0, bir[2])));
            half8 a = *(const half8*)aptr;
            f32x4v d0 = __builtin_amdgcn_mfma_f32_16x16x32_f16(a, whB[0], zC, 0, 0, 0);
            f32x4v d1 = __builtin_amdgcn_mfma_f32_16x16x32_f16(a, whB[1], zC, 0, 0, 0);
            f32x4v d2 = __builtin_amdgcn_mfma_f32_16x16x32_f16(a, whB[2], cN, 0, 0, 0);
            float av = gxr + d0[0];
            float bv = gxz + d1[0];
            float Er = fexp2(fminf(58.f, -av));
            float rg = frcp(1.0f + Er);
            float c2 = fmaf(rg, d2[0], gxn);           // = -2c*log2e
            float Ez = fexp2(fminf(58.f, -bv));
            float Ec = fexp2(fminf(63.f, c2));
            float num = fmaf(hj - Ez, Ec, hj + Ez);
            float den = (1.0f + Ec) * (1.0f + Ez);
            float hn = num * frcp(den);
            hj = hn;
            _Float16 hh = (_Float16)hn;
            hzb[lane] = hh;
            *yw = hh;
            yw += ystep;
        }
    }

    // ================= layers 2..6 =================
    #pragma unroll 1
    for (int l = 0; l < DEPTH; ++l) {
        // gx B-frags, K-split: this lane's k-half serves dir=bdir; lo = y dims
        // 0..15, hi = dims 16..31 of that dir's Wi.
        half8 bflo[3], bfhi[3];
        #pragma unroll
        for (int g = 0; g < 3; ++g) {
            const float scale = (g == 2) ? (-2.0f * L2E) : L2E;
            const float* w = Wi5 + ((size_t)(l * 2 + bdir) * G + g * 16 + j15) * D2;
            half8 lo, hi;
            #pragma unroll
            for (int i = 0; i < 8; ++i) {
                lo[i] = (_Float16)(scale * w[klo + i]);
                hi[i] = (_Float16)(scale * w[16 + klo + i]);
            }
            bflo[g] = lo;
            bfhi[g] = hi;
        }
        // gh B-frags (dir split by quad-half)
        half8 whB[3];
        {
            const float* wsrc = Wh5 + ((size_t)(l * 2) + bdir) * G * H;
            #pragma unroll
            for (int g = 0; g < 3; ++g) {
                const float scale = (g == 2) ? (-2.0f * L2E) : L2E;
                const float* w = wsrc + (g * 16 + j15) * H + klo;
                half8 hv;
                #pragma unroll
                for (int i = 0; i < 8; ++i) hv[i] = (_Float16)(scale * w[i]);
                whB[g] = hv;
            }
        }
        // own-dir biases -> C splats (scaled)
        float bib0, bib1, bib2, bhn2;
        {
            const float* biL = bi5 + (l * 2 + dir) * G;
            const float* bhL = bh5 + (l * 2 + dir) * G;
            bib0 = L2E * (biL[j15]     + bhL[j15]);
            bib1 = L2E * (biL[H + j15] + bhL[H + j15]);
            bib2 = -2.0f * L2E * biL[2 * H + j15];
            bhn2 = -2.0f * L2E * bhL[2 * H + j15];
        }
        const f32x4v cR  = {bib0, bib0, bib0, bib0};
        const f32x4v cZ  = {bib1, bib1, bib1, bib1};
        const f32x4v cNx = {bib2, bib2, bib2, bib2};
        const f32x4v cN  = {bhn2, bhn2, bhn2, bhn2};

        hj = 0.0f;
        hzb[lane] = (_Float16)0.0f;

        // gx A-frag role: rows 0..7 fwd (t = 4c + tl), rows 8..15 bwd
        // (t = T-1-4c - tl, mirrored so C reg s == step s for both dirs).
        const bool fsel = (j15 < 8);
        const int  lb_a = (j15 >> 2) & 1;
        const int  tl_a = j15 & 3;
        const bool axv  = fsel ? (quad < 2) : (quad >= 2);

        unsigned int ypk[16];   // steps k<32, packed 2 f16/reg (static idx)

        // ---- park phase: chunks 0..7 (steps k=0..31) ----
        #pragma unroll
        for (int c = 0; c < 8; ++c) {
            const int trow = fsel ? (4 * c + tl_a) : (T - 1 - 4 * c - tl_a);
            const _Float16* abase = yb + lb_a * YSB + trow * YST;
            half8 alo = *(const half8*)(axv ? (abase + klo)      : (hzb + HZ_ZOFF));
            half8 ahi = *(const half8*)(axv ? (abase + 16 + klo) : (hzb + HZ_ZOFF));
            f32x4v c0 = __builtin_amdgcn_mfma_f32_16x16x32_f16(alo, bflo[0], cR, 0, 0, 0);
            f32x4v c1 = __builtin_amdgcn_mfma_f32_16x16x32_f16(alo, bflo[1], cZ, 0, 0, 0);
            f32x4v c2g = __builtin_amdgcn_mfma_f32_16x16x32_f16(alo, bflo[2], cNx, 0, 0, 0);
            c0  = __builtin_amdgcn_mfma_f32_16x16x32_f16(ahi, bfhi[0], c0, 0, 0, 0);
            c1  = __builtin_amdgcn_mfma_f32_16x16x32_f16(ahi, bfhi[1], c1, 0, 0, 0);
            c2g = __builtin_amdgcn_mfma_f32_16x16x32_f16(ahi, bfhi[2], c2g, 0, 0, 0);

            #pragma unroll
            for (int s = 0; s < 4; ++s) {
                half8 a = *(const half8*)aptr;
                f32x4v d0 = __builtin_amdgcn_mfma_f32_16x16x32_f16(a, whB[0], zC, 0, 0, 0);
                f32x4v d1 = __builtin_amdgcn_mfma_f32_16x16x32_f16(a, whB[1], zC, 0, 0, 0);
                f32x4v d2 = __builtin_amdgcn_mfma_f32_16x16x32_f16(a, whB[2], cN, 0, 0, 0);
                float av = c0[s] + d0[0];
                float bv = c1[s] + d1[0];
                float Er = fexp2(fminf(58.f, -av));
                float rg = frcp(1.0f + Er);
                float cc = fmaf(rg, d2[0], c2g[s]);
                float Ez = fexp2(fminf(58.f, -bv));
                float Ec = fexp2(fminf(63.f, cc));
                float num = fmaf(hj - Ez, Ec, hj + Ez);
                float den = (1.0f + Ec) * (1.0f + Ez);
                float hn = num * frcp(den);
                hj = hn;
                _Float16 hh = (_Float16)hn;
                hzb[lane] = hh;
                unsigned int hb16 = (unsigned int)__builtin_bit_cast(unsigned short, hh);
                if (s & 1) ypk[2 * c + (s >> 1)] |= hb16 << 16;
                else       ypk[2 * c + (s >> 1)]  = hb16;
            }
        }

        // ---- direct phase: chunks 8..15 (steps k=32..63), in-place writes ----
        {
            _Float16* yw = yb + lb * YSB + (isf ? 32 : 31) * YST + dir * H + j15;
            #pragma unroll 1
            for (int c = 8; c < 16; ++c) {
                const int trow = fsel ? (4 * c + tl_a) : (T - 1 - 4 * c - tl_a);
                const _Float16* abase = yb + lb_a * YSB + trow * YST;
                half8 alo = *(const half8*)(axv ? (abase + klo)      : (hzb + HZ_ZOFF));
                half8 ahi = *(const half8*)(axv ? (abase + 16 + klo) : (hzb + HZ_ZOFF));
                f32x4v c0 = __builtin_amdgcn_mfma_f32_16x16x32_f16(alo, bflo[0], cR, 0, 0, 0);
                f32x4v c1 = __builtin_amdgcn_mfma_f32_16x16x32_f16(alo, bflo[1], cZ, 0, 0, 0);
                f32x4v c2g = __builtin_amdgcn_mfma_f32_16x16x32_f16(alo, bflo[2], cNx, 0, 0, 0);
                c0  = __builtin_amdgcn_mfma_f32_16x16x32_f16(ahi, bfhi[0], c0, 0, 0, 0);
                c1  = __builtin_amdgcn_mfma_f32_16x16x32_f16(ahi, bfhi[1], c1, 0, 0, 0);
                c2g = __builtin_amdgcn_mfma_f32_16x16x32_f16(ahi, bfhi[2], c2g, 0, 0, 0);

                #pragma unroll
                for (int s = 0; s < 4; ++s) {
                    half8 a = *(const half8*)aptr;
                    f32x4v d0 = __builtin_amdgcn_mfma_f32_16x16x32_f16(a, whB[0], zC, 0, 0, 0);
                    f32x4v d1 = __builtin_amdgcn_mfma_f32_16x16x32_f16(a, whB[1], zC, 0, 0, 0);
                    f32x4v d2 = __builtin_amdgcn_mfma_f32_16x16x32_f16(a, whB[2], cN, 0, 0, 0);
                    float av = c0[s] + d0[0];
                    float bv = c1[s] + d1[0];
                    float Er = fexp2(fminf(58.f, -av));
                    float rg = frcp(1.0f + Er);
                    float cc = fmaf(rg, d2[0], c2g[s]);
                    float Ez = fexp2(fminf(58.f, -bv));
                    float Ec = fexp2(fminf(63.f, cc));
                    float num = fmaf(hj - Ez, Ec, hj + Ez);
                    float den = (1.0f + Ec) * (1.0f + Ez);
                    float hn = num * frcp(den);
                    hj = hn;
                    _Float16 hh = (_Float16)hn;
                    hzb[lane] = hh;
                    *yw = hh;
                    yw += ystep;
                }
            }
        }

        // ---- dump parked half (rows 0..31 fwd / 63..32 bwd) ----
        {
            _Float16* yw = yb + lb * YSB + (isf ? 0 : (T - 1)) * YST + dir * H + j15;
            #pragma unroll
            for (int i = 0; i < 16; ++i) {
                unsigned int v = ypk[i];
                *yw = __builtin_bit_cast(_Float16, (unsigned short)(v & 0xffffu));
                yw += ystep;
                *yw = __builtin_bit_cast(_Float16, (unsigned short)(v >> 16));
                yw += ystep;
            }
        }
    }

    // ================= classifier + softmax (final y in yb) =================
    #pragma unroll
    for (int i = 0; i < 2; ++i) {
        int idx = lane + i * 64;
        int bb  = idx >> 6;
        int t   = idx & 63;
        const _Float16* yrow = yb + bb * YSB + t * YST;
        float yv[D2];
        #pragma unroll
        for (int k8 = 0; k8 < 4; ++k8) {
            half8 v = *(const half8*)(yrow + k8 * 8);
            #pragma unroll
            for (int i8 = 0; i8 < 8; ++i8) yv[k8 * 8 + i8] = (float)v[i8];
        }
        float lg[NCLS];
        #pragma unroll
        for (int c = 0; c < NCLS; ++c) {
            const float* wc = Wc + c * D2;
            float acc = bc[c];
            #pragma unroll
            for (int k = 0; k < D2; ++k) acc = fmaf(wc[k], yv[k], acc);
            lg[c] = acc;
        }
        float m = fmaxf(fmaxf(lg[0], lg[1]), fmaxf(lg[2], lg[3]));
        float e0 = __expf(lg[0] - m), e1 = __expf(lg[1] - m);
        float e2 = __expf(lg[2] - m), e3 = __expf(lg[3] - m);
        float inv = frcp(e0 + e1 + e2 + e3);
        size_t bglob = (size_t)blockIdx.x * 2 + bb;
        float4 o;
        o.x = e0 * inv; o.y = e1 * inv; o.z = e2 * inv; o.w = e3 * inv;
        ((float4*)out)[bglob * T + t] = o;
    }
}

extern "C" void kernel_launch(void* const* d_in, const int* in_sizes, int n_in,
                              void* d_out, int out_size, void* d_ws, size_t ws_size,
                              hipStream_t stream) {
    const float* x   = (const float*)d_in[0];
    const float* Wi1 = (const float*)d_in[1];
    const float* Wh1 = (const float*)d_in[2];
    const float* bi1 = (const float*)d_in[3];
    const float* bh1 = (const float*)d_in[4];
    const float* Wi5 = (const float*)d_in[5];
    const float* Wh5 = (const float*)d_in[6];
    const float* bi5 = (const float*)d_in[7];
    const float* bh5 = (const float*)d_in[8];
    const float* Wc  = (const float*)d_in[9];
    const float* bc  = (const float*)d_in[10];
    float* out = (float*)d_out;

    const int B = in_sizes[0] / (T * F_IN);   // 16384
    dim3 grid(B / 2), block(64);
    hipLaunchKernelGGL(bigru_all, grid, block, 0, stream,
                       x, Wi1, Wh1, bi1, bh1, Wi5, Wh5, bi5, bh5, Wc, bc, out);
}